// Round 1
// baseline (1399.467 us; speedup 1.0000x reference)
//
#include <hip/hip_runtime.h>
#include <math.h>

#define NN 100000
#define NE 1600000
#define NG 512
#define HID 64
#define NH 4
#define INF_ 32
#define EF 16
#define NCLS 10
#define NEG 0.2f
#define BNEPS 1e-5f
#define BNB 1e-4f

// ---------------- BatchNorm stats (two-stage, deterministic) ----------------
template<int C>
__global__ __launch_bounds__(256) void k_bn_part(const float* __restrict__ x, int rows,
                                                 float* __restrict__ part) {
    const int RPI = 256 / C;
    int col = threadIdx.x % C;
    int sub = threadIdx.x / C;
    int nb = gridDim.x;
    int rpb = (rows + nb - 1) / nb;
    int r0 = blockIdx.x * rpb;
    int r1 = min(rows, r0 + rpb);
    float s = 0.f, q = 0.f;
    for (int r = r0 + sub; r < r1; r += RPI) {
        float v = x[(size_t)r * C + col];
        s += v; q += v * v;
    }
    __shared__ float ls[256], lq[256];
    ls[threadIdx.x] = s; lq[threadIdx.x] = q;
    __syncthreads();
    for (int st = RPI / 2; st > 0; st >>= 1) {
        if (sub < st) {
            ls[threadIdx.x] += ls[threadIdx.x + st * C];
            lq[threadIdx.x] += lq[threadIdx.x + st * C];
        }
        __syncthreads();
    }
    if (sub == 0) {
        part[(size_t)blockIdx.x * C + col] = ls[col];
        part[(size_t)(nb + blockIdx.x) * C + col] = lq[col];
    }
}

__global__ __launch_bounds__(64) void k_bn_final(const float* __restrict__ part, int nb, int rows,
                                                 int C, float* __restrict__ sc, float* __restrict__ sh) {
    int c = threadIdx.x;
    if (c >= C) return;
    float s = 0.f, q = 0.f;
    for (int b = 0; b < nb; b++) {
        s += part[(size_t)b * C + c];
        q += part[(size_t)(nb + b) * C + c];
    }
    float mu = s / rows;
    float var = q / rows - mu * mu;
    float sl = rsqrtf(var + BNEPS);
    sc[c] = sl;
    sh[c] = BNB - mu * sl;
}

// badj[j] = opt_b[j] + sum_k sh[k]*W[k][j]
__global__ __launch_bounds__(64) void k_adjbias(const float* __restrict__ sh, const float* __restrict__ W,
                                                const float* __restrict__ b, int K, int Ncol,
                                                float* __restrict__ badj) {
    int j = threadIdx.x;
    if (j >= Ncol) return;
    float a = b ? b[j] : 0.f;
    for (int k = 0; k < K; k++) a += sh[k] * W[(size_t)k * Ncol + j];
    badj[j] = a;
}

// out[r][j] = (x[r]*sc) @ W + badj[j], optional relu. W is [K][64].
template<int K, bool RELU>
__global__ __launch_bounds__(256) void k_gemm_bn(const float* __restrict__ x, const float* __restrict__ W,
                                                 const float* __restrict__ sc, const float* __restrict__ badj,
                                                 float* __restrict__ out, int rows) {
    __shared__ float Ws[K * 64];
    __shared__ float Xs[32 * K];
    int r0 = blockIdx.x * 32;
    for (int i = threadIdx.x; i < K * 64; i += 256) Ws[i] = W[i];
    for (int i = threadIdx.x; i < 32 * K; i += 256) {
        int r = r0 + i / K, k = i % K;
        Xs[i] = (r < rows) ? x[(size_t)r * K + k] * sc[k] : 0.f;
    }
    __syncthreads();
    int col = threadIdx.x & 63;
    int rg = threadIdx.x >> 6;
    float b0 = badj[col];
    float acc[8];
#pragma unroll
    for (int i = 0; i < 8; i++) acc[i] = b0;
    for (int k = 0; k < K; k++) {
        float w = Ws[k * 64 + col];
#pragma unroll
        for (int i = 0; i < 8; i++) acc[i] += Xs[(rg * 8 + i) * K + k] * w;
    }
#pragma unroll
    for (int i = 0; i < 8; i++) {
        int r = r0 + rg * 8 + i;
        if (r < rows) out[(size_t)r * 64 + col] = RELU ? fmaxf(acc[i], 0.f) : acc[i];
    }
}

// hs[n] = h[n,:] . att
__global__ __launch_bounds__(256) void k_hs(const float* __restrict__ h, const float* __restrict__ att,
                                            float* __restrict__ hs, int N) {
    int n = blockIdx.x * 4 + (threadIdx.x >> 6);
    int lane = threadIdx.x & 63;
    if (n >= N) return;
    float v = h[(size_t)n * 64 + lane] * att[lane];
#pragma unroll
    for (int o = 32; o; o >>= 1) v += __shfl_xor(v, o);
    if (lane == 0) hs[n] = v;
}

// a_src[n,h], a_dst[n,h] per head (16-lane group reductions)
__global__ __launch_bounds__(256) void k_attnode(const float* __restrict__ hh, const float* __restrict__ as_,
                                                 const float* __restrict__ ad_, float* __restrict__ asrc,
                                                 float* __restrict__ adst, int N) {
    int n = blockIdx.x * 4 + (threadIdx.x >> 6);
    int lane = threadIdx.x & 63;
    if (n >= N) return;
    float v = hh[(size_t)n * 64 + lane];
    float s1 = v * as_[lane], s2 = v * ad_[lane];
#pragma unroll
    for (int o = 1; o < 16; o <<= 1) { s1 += __shfl_xor(s1, o); s2 += __shfl_xor(s2, o); }
    if ((lane & 15) == 0) {
        asrc[(size_t)n * 4 + (lane >> 4)] = s1;
        adst[(size_t)n * 4 + (lane >> 4)] = s2;
    }
}

// wE[l][h][k] = sum_d We[l][k][h*16+d] * atte[l][h][d]
__global__ __launch_bounds__(768) void k_we(const float* __restrict__ We, const float* __restrict__ atte,
                                            float* __restrict__ wE) {
    int t = threadIdx.x;
    if (t >= 768) return;
    int l = t >> 8;
    int h = (t >> 6) & 3;
    int k = t & 63;
    float a = 0.f;
    for (int d = 0; d < 16; d++)
        a += We[(size_t)l * 4096 + k * 64 + h * 16 + d] * atte[l * 64 + h * 16 + d];
    wE[t] = a;
}

// ---------------- CSR build ----------------
__global__ __launch_bounds__(256) void k_hist(const int* __restrict__ dst, int* __restrict__ deg) {
    int e = blockIdx.x * 256 + threadIdx.x;
    if (e < NE) atomicAdd(&deg[dst[e]], 1);
}

__global__ __launch_bounds__(256) void k_chunksum(const int* __restrict__ deg, int* __restrict__ psum) {
    __shared__ int ls[256];
    int i = blockIdx.x * 512 + threadIdx.x;
    int v = 0;
    if (i < NN) v = deg[i];
    if (i + 256 < NN) v += deg[i + 256];
    ls[threadIdx.x] = v;
    __syncthreads();
    for (int st = 128; st; st >>= 1) {
        if ((int)threadIdx.x < st) ls[threadIdx.x] += ls[threadIdx.x + st];
        __syncthreads();
    }
    if (threadIdx.x == 0) psum[blockIdx.x] = ls[0];
}

// exclusive scan of chunk sums (nchunk <= 256), also writes rowp[NN] = total
__global__ __launch_bounds__(256) void k_scantop(int* __restrict__ psum, int nchunk, int* __restrict__ rowp) {
    __shared__ int ls[256];
    int t = threadIdx.x;
    int v = (t < nchunk) ? psum[t] : 0;
    ls[t] = v;
    __syncthreads();
    for (int st = 1; st < 256; st <<= 1) {
        int a = (t >= st) ? ls[t - st] : 0;
        __syncthreads();
        ls[t] += a;
        __syncthreads();
    }
    if (t < nchunk) psum[t] = ls[t] - v;  // exclusive
    if (t == 255) rowp[NN] = ls[255];
}

__global__ __launch_bounds__(512) void k_scanwrite(const int* __restrict__ deg, const int* __restrict__ psum,
                                                   int* __restrict__ rowp) {
    __shared__ int ls[512];
    int i = blockIdx.x * 512 + threadIdx.x;
    int v = (i < NN) ? deg[i] : 0;
    ls[threadIdx.x] = v;
    __syncthreads();
    for (int st = 1; st < 512; st <<= 1) {
        int a = ((int)threadIdx.x >= st) ? ls[threadIdx.x - st] : 0;
        __syncthreads();
        ls[threadIdx.x] += a;
        __syncthreads();
    }
    if (i < NN) rowp[i] = psum[blockIdx.x] + ls[threadIdx.x] - v;
}

__global__ __launch_bounds__(256) void k_scatter(const int* __restrict__ src, const int* __restrict__ dst,
                                                 int* __restrict__ cursor, int* __restrict__ srcS,
                                                 int* __restrict__ epos) {
    int e = blockIdx.x * 256 + threadIdx.x;
    if (e >= NE) return;
    int d = dst[e];
    int p = atomicAdd(&cursor[d], 1);
    srcS[p] = src[e];
    epos[e] = p;
}

// ---------------- edge precompute: he = ea@We+be ; heatt = he.att ; aed[l][h] = relu(he).wE ----------------
__global__ __launch_bounds__(256) void k_edgepre(const float* __restrict__ ea, const float* __restrict__ We,
                                                 const float* __restrict__ be, const float* __restrict__ att,
                                                 const float* __restrict__ wE, const int* __restrict__ epos,
                                                 float* __restrict__ heatt, float4* __restrict__ aed) {
    int e = blockIdx.x * 256 + threadIdx.x;
    if (e >= NE) return;
    const float4* eav = (const float4*)(ea + (size_t)e * 16);
    float4 A0 = eav[0], A1 = eav[1], A2 = eav[2], A3 = eav[3];
    float a[16] = {A0.x, A0.y, A0.z, A0.w, A1.x, A1.y, A1.z, A1.w,
                   A2.x, A2.y, A2.z, A2.w, A3.x, A3.y, A3.z, A3.w};
    float he[64];
#pragma unroll
    for (int j = 0; j < 64; j++) he[j] = be[j];
#pragma unroll
    for (int k = 0; k < 16; k++) {
        float s = a[k];
#pragma unroll
        for (int j = 0; j < 64; j++) he[j] += s * We[k * 64 + j];
    }
    float hatt = 0.f;
#pragma unroll
    for (int j = 0; j < 64; j++) hatt += he[j] * att[j];
#pragma unroll
    for (int j = 0; j < 64; j++) he[j] = fmaxf(he[j], 0.f);
    int p = epos[e];
    heatt[p] = hatt;
#pragma unroll
    for (int l = 0; l < 3; l++) {
        float s0 = 0.f, s1 = 0.f, s2 = 0.f, s3 = 0.f;
#pragma unroll
        for (int j = 0; j < 64; j++) {
            float r = he[j];
            s0 += r * wE[(l * 4 + 0) * 64 + j];
            s1 += r * wE[(l * 4 + 1) * 64 + j];
            s2 += r * wE[(l * 4 + 2) * 64 + j];
            s3 += r * wE[(l * 4 + 3) * 64 + j];
        }
        float4 o; o.x = s0; o.y = s1; o.z = s2; o.w = s3;
        aed[(size_t)l * NE + p] = o;
    }
}

// ---------------- EGAT aggregation (1 wave per node) ----------------
__global__ __launch_bounds__(64) void k_egat_agg(const int* __restrict__ rowp, const int* __restrict__ srcS,
                                                 const float* __restrict__ heatt, const float* __restrict__ hs,
                                                 const float* __restrict__ h, float* __restrict__ xout) {
    int n = blockIdx.x;
    int lane = threadIdx.x;
    int beg = rowp[n], deg = rowp[n + 1] - beg;
    float hsn = hs[n];
    float mx = -INFINITY;
    for (int i = lane; i < deg; i += 64) {
        int s = srcS[beg + i];
        float lg = hs[s] + hsn + heatt[beg + i];
        lg = lg > 0.f ? lg : NEG * lg;
        mx = fmaxf(mx, lg);
    }
#pragma unroll
    for (int o = 32; o; o >>= 1) mx = fmaxf(mx, __shfl_xor(mx, o));
    float sm = 0.f;
    for (int i = lane; i < deg; i += 64) {
        int s = srcS[beg + i];
        float lg = hs[s] + hsn + heatt[beg + i];
        lg = lg > 0.f ? lg : NEG * lg;
        sm += expf(lg - mx);
    }
#pragma unroll
    for (int o = 32; o; o >>= 1) sm += __shfl_xor(sm, o);
    float inv = deg > 0 ? 1.f / sm : 0.f;
    __shared__ float pl[64];
    __shared__ int sl[64];
    float acc = 0.f;
    for (int base = 0; base < deg; base += 64) {
        int i = base + lane;
        if (i < deg) {
            int s = srcS[beg + i];
            float lg = hs[s] + hsn + heatt[beg + i];
            lg = lg > 0.f ? lg : NEG * lg;
            pl[lane] = expf(lg - mx) * inv;
            sl[lane] = s;
        }
        __syncthreads();
        int mm = min(64, deg - base);
        int j = 0;
        for (; j + 4 <= mm; j += 4) {
            acc += pl[j] * h[(size_t)sl[j] * 64 + lane];
            acc += pl[j + 1] * h[(size_t)sl[j + 1] * 64 + lane];
            acc += pl[j + 2] * h[(size_t)sl[j + 2] * 64 + lane];
            acc += pl[j + 3] * h[(size_t)sl[j + 3] * 64 + lane];
        }
        for (; j < mm; j++) acc += pl[j] * h[(size_t)sl[j] * 64 + lane];
        __syncthreads();
    }
    xout[(size_t)n * 64 + lane] = fmaxf(acc, 0.f);
}

// ---------------- conv (GATConv) aggregation, 4 heads ----------------
__global__ __launch_bounds__(64) void k_conv_agg(const int* __restrict__ rowp, const int* __restrict__ srcS,
                                                 const float4* __restrict__ aed, const float* __restrict__ asrc,
                                                 const float* __restrict__ adst, const float* __restrict__ hh,
                                                 const float* __restrict__ bias, float* __restrict__ xout) {
    int n = blockIdx.x;
    int lane = threadIdx.x;
    int beg = rowp[n], deg = rowp[n + 1] - beg;
    float4 an = ((const float4*)adst)[n];
    float m0 = -INFINITY, m1 = -INFINITY, m2 = -INFINITY, m3 = -INFINITY;
    for (int i = lane; i < deg; i += 64) {
        int s = srcS[beg + i];
        float4 as4 = ((const float4*)asrc)[s];
        float4 ae = aed[beg + i];
        float l0 = as4.x + an.x + ae.x; l0 = l0 > 0.f ? l0 : NEG * l0;
        float l1 = as4.y + an.y + ae.y; l1 = l1 > 0.f ? l1 : NEG * l1;
        float l2 = as4.z + an.z + ae.z; l2 = l2 > 0.f ? l2 : NEG * l2;
        float l3 = as4.w + an.w + ae.w; l3 = l3 > 0.f ? l3 : NEG * l3;
        m0 = fmaxf(m0, l0); m1 = fmaxf(m1, l1); m2 = fmaxf(m2, l2); m3 = fmaxf(m3, l3);
    }
#pragma unroll
    for (int o = 32; o; o >>= 1) {
        m0 = fmaxf(m0, __shfl_xor(m0, o)); m1 = fmaxf(m1, __shfl_xor(m1, o));
        m2 = fmaxf(m2, __shfl_xor(m2, o)); m3 = fmaxf(m3, __shfl_xor(m3, o));
    }
    float s0 = 0.f, s1 = 0.f, s2 = 0.f, s3 = 0.f;
    for (int i = lane; i < deg; i += 64) {
        int s = srcS[beg + i];
        float4 as4 = ((const float4*)asrc)[s];
        float4 ae = aed[beg + i];
        float l0 = as4.x + an.x + ae.x; l0 = l0 > 0.f ? l0 : NEG * l0;
        float l1 = as4.y + an.y + ae.y; l1 = l1 > 0.f ? l1 : NEG * l1;
        float l2 = as4.z + an.z + ae.z; l2 = l2 > 0.f ? l2 : NEG * l2;
        float l3 = as4.w + an.w + ae.w; l3 = l3 > 0.f ? l3 : NEG * l3;
        s0 += expf(l0 - m0); s1 += expf(l1 - m1); s2 += expf(l2 - m2); s3 += expf(l3 - m3);
    }
#pragma unroll
    for (int o = 32; o; o >>= 1) {
        s0 += __shfl_xor(s0, o); s1 += __shfl_xor(s1, o);
        s2 += __shfl_xor(s2, o); s3 += __shfl_xor(s3, o);
    }
    float i0 = deg > 0 ? 1.f / s0 : 0.f;
    float i1 = deg > 0 ? 1.f / s1 : 0.f;
    float i2 = deg > 0 ? 1.f / s2 : 0.f;
    float i3 = deg > 0 ? 1.f / s3 : 0.f;
    __shared__ float pls[4 * 65];  // stride 65 -> 4 head rows land on distinct banks
    __shared__ int sl[64];
    float acc = 0.f;
    int hq = lane >> 4;
    for (int base = 0; base < deg; base += 64) {
        int i = base + lane;
        if (i < deg) {
            int s = srcS[beg + i];
            float4 as4 = ((const float4*)asrc)[s];
            float4 ae = aed[beg + i];
            float l0 = as4.x + an.x + ae.x; l0 = l0 > 0.f ? l0 : NEG * l0;
            float l1 = as4.y + an.y + ae.y; l1 = l1 > 0.f ? l1 : NEG * l1;
            float l2 = as4.z + an.z + ae.z; l2 = l2 > 0.f ? l2 : NEG * l2;
            float l3 = as4.w + an.w + ae.w; l3 = l3 > 0.f ? l3 : NEG * l3;
            pls[0 * 65 + lane] = expf(l0 - m0) * i0;
            pls[1 * 65 + lane] = expf(l1 - m1) * i1;
            pls[2 * 65 + lane] = expf(l2 - m2) * i2;
            pls[3 * 65 + lane] = expf(l3 - m3) * i3;
            sl[lane] = s;
        }
        __syncthreads();
        int mm = min(64, deg - base);
        const float* prow = &pls[hq * 65];
        int j = 0;
        for (; j + 4 <= mm; j += 4) {
            acc += prow[j] * hh[(size_t)sl[j] * 64 + lane];
            acc += prow[j + 1] * hh[(size_t)sl[j + 1] * 64 + lane];
            acc += prow[j + 2] * hh[(size_t)sl[j + 2] * 64 + lane];
            acc += prow[j + 3] * hh[(size_t)sl[j + 3] * 64 + lane];
        }
        for (; j < mm; j++) acc += prow[j] * hh[(size_t)sl[j] * 64 + lane];
        __syncthreads();
    }
    xout[(size_t)n * 64 + lane] = fmaxf(acc + bias[lane], 0.f);
}

// ---------------- pool + head ----------------
__device__ __forceinline__ int lowerb(const int* a, int n, int key) {
    int lo = 0, hi = n;
    while (lo < hi) {
        int mid = (lo + hi) >> 1;
        if (a[mid] < key) lo = mid + 1; else hi = mid;
    }
    return lo;
}

__global__ __launch_bounds__(64) void k_pool(const float* __restrict__ x, const int* __restrict__ batch,
                                             float* __restrict__ g) {
    int gr = blockIdx.x, lane = threadIdx.x;
    int beg = lowerb(batch, NN, gr);
    int end = lowerb(batch, NN, gr + 1);
    float acc = 0.f;
    for (int i = beg; i < end; i++) acc += x[(size_t)i * 64 + lane];
    g[(size_t)gr * 64 + lane] = acc;
}

__global__ __launch_bounds__(64) void k_cls(const float* __restrict__ y, const float* __restrict__ W,
                                            const float* __restrict__ sc, const float* __restrict__ badj,
                                            float* __restrict__ out) {
    int r = blockIdx.x, lane = threadIdx.x;
    __shared__ float yr[64];
    yr[lane] = y[(size_t)r * 64 + lane] * sc[lane];
    __syncthreads();
    float lg = -INFINITY;
    if (lane < NCLS) {
        float a = badj[lane];
        for (int k = 0; k < 64; k++) a += yr[k] * W[k * NCLS + lane];
        lg = a;
    }
    float mx = lg;
#pragma unroll
    for (int o = 32; o; o >>= 1) mx = fmaxf(mx, __shfl_xor(mx, o));
    float e = (lane < NCLS) ? expf(lg - mx) : 0.f;
    float s = e;
#pragma unroll
    for (int o = 32; o; o >>= 1) s += __shfl_xor(s, o);
    if (lane < NCLS) out[(size_t)r * NCLS + lane] = lg - mx - logf(s);
}

extern "C" void kernel_launch(void* const* d_in, const int* in_sizes, int n_in,
                              void* d_out, int out_size, void* d_ws, size_t ws_size,
                              hipStream_t stream) {
    const float* x0  = (const float*)d_in[0];
    const float* ea  = (const float*)d_in[1];
    const int* eidx  = (const int*)d_in[2];
    const int* batch = (const int*)d_in[3];
    const float* Wx  = (const float*)d_in[4];
    const float* bx  = (const float*)d_in[5];
    const float* Wee = (const float*)d_in[6];
    const float* bee = (const float*)d_in[7];
    const float* att = (const float*)d_in[8];
    const float* cW  = (const float*)d_in[9];
    const float* cWe = (const float*)d_in[10];
    const float* cas = (const float*)d_in[11];
    const float* cad = (const float*)d_in[12];
    const float* cae = (const float*)d_in[13];
    const float* cb  = (const float*)d_in[14];
    const float* lW  = (const float*)d_in[15];
    const float* lb  = (const float*)d_in[16];
    const float* clW = (const float*)d_in[17];
    const float* clb = (const float*)d_in[18];
    float* out = (float*)d_out;

    const int* srcA = eidx;
    const int* dstA = eidx + NE;

    char* w = (char*)d_ws;
    size_t off = 0;
    auto alloc = [&](size_t bytes) -> void* {
        void* p = w + off;
        off += (bytes + 255) & ~(size_t)255;
        return p;
    };
    float* A      = (float*)alloc((size_t)NN * 64 * 4);
    float* B      = (float*)alloc((size_t)NN * 64 * 4);
    float* hs     = (float*)alloc((size_t)NN * 4);
    float* asrc   = (float*)alloc((size_t)NN * 4 * 4);
    float* adst   = (float*)alloc((size_t)NN * 4 * 4);
    float* heatt  = (float*)alloc((size_t)NE * 4);
    float4* aed   = (float4*)alloc((size_t)3 * NE * 16);
    int* srcS     = (int*)alloc((size_t)NE * 4);
    int* epos     = (int*)alloc((size_t)NE * 4);
    int* rowp     = (int*)alloc((size_t)(NN + 1) * 4);
    int* deg      = (int*)alloc((size_t)NN * 4);
    int* cursor   = (int*)alloc((size_t)NN * 4);
    int* psum     = (int*)alloc(4096);
    float* part   = (float*)alloc((size_t)2 * 200 * 64 * 4);
    float* sc     = (float*)alloc(64 * 4);
    float* sh     = (float*)alloc(64 * 4);
    float* badj   = (float*)alloc(64 * 4);
    float* wE     = (float*)alloc(768 * 4);
    float* g      = (float*)alloc((size_t)NG * 64 * 4);
    float* y      = (float*)alloc((size_t)NG * 64 * 4);
    float* badj2  = (float*)alloc(64 * 4);
    float* badj3  = (float*)alloc(64 * 4);
    if (off > ws_size) return;  // workspace too small; bail (will fail validation visibly)

    const int NB = 200;
    const int NCHUNK = (NN + 511) / 512;  // 196 (<=256 for k_scantop)

    // ---- CSR build (by dst) ----
    hipMemsetAsync(deg, 0, (size_t)NN * 4, stream);
    k_hist<<<(NE + 255) / 256, 256, 0, stream>>>(dstA, deg);
    k_chunksum<<<NCHUNK, 256, 0, stream>>>(deg, psum);
    k_scantop<<<1, 256, 0, stream>>>(psum, NCHUNK, rowp);
    k_scanwrite<<<NCHUNK, 512, 0, stream>>>(deg, psum, rowp);
    hipMemcpyAsync(cursor, rowp, (size_t)NN * 4, hipMemcpyDeviceToDevice, stream);
    k_scatter<<<(NE + 255) / 256, 256, 0, stream>>>(srcA, dstA, cursor, srcS, epos);

    // ---- folded edge-attention weights ----
    k_we<<<1, 768, 0, stream>>>(cWe, cae, wE);

    // ---- BN(x0) folded into EGAT node GEMM: A = h ----
    k_bn_part<32><<<NB, 256, 0, stream>>>(x0, NN, part);
    k_bn_final<<<1, 64, 0, stream>>>(part, NB, NN, 32, sc, sh);
    k_adjbias<<<1, 64, 0, stream>>>(sh, Wx, bx, 32, 64, badj);
    k_gemm_bn<32, false><<<(NN + 31) / 32, 256, 0, stream>>>(x0, Wx, sc, badj, A, NN);
    k_hs<<<(NN + 3) / 4, 256, 0, stream>>>(A, att, hs, NN);

    // ---- edge precompute (he, heatt, per-layer a_edge) ----
    k_edgepre<<<(NE + 255) / 256, 256, 0, stream>>>(ea, Wee, bee, att, wE, epos, heatt, aed);

    // ---- EGAT aggregation: B = relu(segsum(alpha * h[src])) ----
    k_egat_agg<<<NN, 64, 0, stream>>>(rowp, srcS, heatt, hs, A, B);

    // ---- 3 GATConv layers ----
    for (int l = 0; l < 3; l++) {
        k_bn_part<64><<<NB, 256, 0, stream>>>(B, NN, part);
        k_bn_final<<<1, 64, 0, stream>>>(part, NB, NN, 64, sc, sh);
        k_adjbias<<<1, 64, 0, stream>>>(sh, cW + (size_t)l * 4096, nullptr, 64, 64, badj);
        k_gemm_bn<64, false><<<(NN + 31) / 32, 256, 0, stream>>>(B, cW + (size_t)l * 4096, sc, badj, A, NN);
        k_attnode<<<(NN + 3) / 4, 256, 0, stream>>>(A, cas + l * 64, cad + l * 64, asrc, adst, NN);
        k_conv_agg<<<NN, 64, 0, stream>>>(rowp, srcS, aed + (size_t)l * NE, asrc, adst, A,
                                          cb + l * 64, B);
    }

    // ---- global add pool ----
    k_pool<<<NG, 64, 0, stream>>>(B, batch, g);

    // ---- head: BN -> lin+relu -> BN -> cls -> log_softmax ----
    k_bn_part<64><<<2, 256, 0, stream>>>(g, NG, part);
    k_bn_final<<<1, 64, 0, stream>>>(part, 2, NG, 64, sc, sh);
    k_adjbias<<<1, 64, 0, stream>>>(sh, lW, lb, 64, 64, badj2);
    k_gemm_bn<64, true><<<(NG + 31) / 32, 256, 0, stream>>>(g, lW, sc, badj2, y, NG);

    k_bn_part<64><<<2, 256, 0, stream>>>(y, NG, part);
    k_bn_final<<<1, 64, 0, stream>>>(part, 2, NG, 64, sc, sh);
    k_adjbias<<<1, 64, 0, stream>>>(sh, clW, clb, 64, 10, badj3);
    k_cls<<<NG, 64, 0, stream>>>(y, clW, sc, badj3, out);
}

// Round 2
// 1326.351 us; speedup vs baseline: 1.0551x; 1.0551x over previous
//
#include <hip/hip_runtime.h>
#include <math.h>

#define NN 100000
#define NE 1600000
#define NG 512
#define NCLS 10
#define NEG 0.2f
#define BNEPS 1e-5f
#define BNB 1e-4f
#define MNEG -1e30f

// ---------------- BatchNorm stats (two-stage, deterministic) ----------------
template<int C>
__global__ __launch_bounds__(256) void k_bn_part(const float* __restrict__ x, int rows,
                                                 float* __restrict__ part) {
    const int RPI = 256 / C;
    int col = threadIdx.x % C;
    int sub = threadIdx.x / C;
    int nb = gridDim.x;
    int rpb = (rows + nb - 1) / nb;
    int r0 = blockIdx.x * rpb;
    int r1 = min(rows, r0 + rpb);
    float s = 0.f, q = 0.f;
    for (int r = r0 + sub; r < r1; r += RPI) {
        float v = x[(size_t)r * C + col];
        s += v; q += v * v;
    }
    __shared__ float ls[256], lq[256];
    ls[threadIdx.x] = s; lq[threadIdx.x] = q;
    __syncthreads();
    for (int st = RPI / 2; st > 0; st >>= 1) {
        if (sub < st) {
            ls[threadIdx.x] += ls[threadIdx.x + st * C];
            lq[threadIdx.x] += lq[threadIdx.x + st * C];
        }
        __syncthreads();
    }
    if (sub == 0) {
        part[(size_t)blockIdx.x * C + col] = ls[col];
        part[(size_t)(nb + blockIdx.x) * C + col] = lq[col];
    }
}

__global__ __launch_bounds__(64) void k_bn_final(const float* __restrict__ part, int nb, int rows,
                                                 int C, float* __restrict__ sc, float* __restrict__ sh) {
    int c = threadIdx.x;
    if (c >= C) return;
    float s = 0.f, q = 0.f;
    for (int b = 0; b < nb; b++) {
        s += part[(size_t)b * C + c];
        q += part[(size_t)(nb + b) * C + c];
    }
    float mu = s / rows;
    float var = q / rows - mu * mu;
    float sl = rsqrtf(var + BNEPS);
    sc[c] = sl;
    sh[c] = BNB - mu * sl;
}

// badj[j] = opt_b[j] + sum_k sh[k]*W[k][j]
__global__ __launch_bounds__(64) void k_adjbias(const float* __restrict__ sh, const float* __restrict__ W,
                                                const float* __restrict__ b, int K, int Ncol,
                                                float* __restrict__ badj) {
    int j = threadIdx.x;
    if (j >= Ncol) return;
    float a = b ? b[j] : 0.f;
    for (int k = 0; k < K; k++) a += sh[k] * W[(size_t)k * Ncol + j];
    badj[j] = a;
}

// out[r][j] = (x[r]*sc) @ W + badj[j], optional relu. W is [K][64].
// EPI=1: also hs[r] = out_row . att    (full-wave reduce)
// EPI=2: also asrc[r][h] = out_row_h . as_, adst likewise (16-lane reduces)
template<int K, bool RELU, int EPI>
__global__ __launch_bounds__(256) void k_gemm_bn(const float* __restrict__ x, const float* __restrict__ W,
                                                 const float* __restrict__ sc, const float* __restrict__ badj,
                                                 float* __restrict__ out, int rows,
                                                 const float* __restrict__ att, float* __restrict__ hs,
                                                 const float* __restrict__ as_, const float* __restrict__ ad_,
                                                 float* __restrict__ asrc, float* __restrict__ adst) {
    __shared__ float Ws[K * 64];
    __shared__ float Xs[32 * K];
    int r0 = blockIdx.x * 32;
    for (int i = threadIdx.x; i < K * 64; i += 256) Ws[i] = W[i];
    for (int i = threadIdx.x; i < 32 * K; i += 256) {
        int r = r0 + i / K, k = i % K;
        Xs[i] = (r < rows) ? x[(size_t)r * K + k] * sc[k] : 0.f;
    }
    __syncthreads();
    int col = threadIdx.x & 63;
    int rg = threadIdx.x >> 6;
    float b0 = badj[col];
    float acc[8];
#pragma unroll
    for (int i = 0; i < 8; i++) acc[i] = b0;
    for (int k = 0; k < K; k++) {
        float w = Ws[k * 64 + col];
#pragma unroll
        for (int i = 0; i < 8; i++) acc[i] += Xs[(rg * 8 + i) * K + k] * w;
    }
#pragma unroll
    for (int i = 0; i < 8; i++) {
        int r = r0 + rg * 8 + i;
        if (r < rows) out[(size_t)r * 64 + col] = RELU ? fmaxf(acc[i], 0.f) : acc[i];
    }
    if (EPI == 1) {
        float a = att[col];
#pragma unroll
        for (int i = 0; i < 8; i++) {
            float v = acc[i] * a;
#pragma unroll
            for (int o = 32; o; o >>= 1) v += __shfl_xor(v, o);
            int r = r0 + rg * 8 + i;
            if (col == 0 && r < rows) hs[r] = v;
        }
    }
    if (EPI == 2) {
        float a1 = as_[col], a2 = ad_[col];
#pragma unroll
        for (int i = 0; i < 8; i++) {
            float s1 = acc[i] * a1, s2 = acc[i] * a2;
#pragma unroll
            for (int o = 1; o < 16; o <<= 1) { s1 += __shfl_xor(s1, o); s2 += __shfl_xor(s2, o); }
            int r = r0 + rg * 8 + i;
            if ((col & 15) == 0 && r < rows) {
                asrc[(size_t)r * 4 + (col >> 4)] = s1;
                adst[(size_t)r * 4 + (col >> 4)] = s2;
            }
        }
    }
}

// wE[l][h][k] = sum_d We[l][k][h*16+d] * atte[l][h][d]
__global__ __launch_bounds__(768) void k_we(const float* __restrict__ We, const float* __restrict__ atte,
                                            float* __restrict__ wE) {
    int t = threadIdx.x;
    if (t >= 768) return;
    int l = t >> 8;
    int h = (t >> 6) & 3;
    int k = t & 63;
    float a = 0.f;
    for (int d = 0; d < 16; d++)
        a += We[(size_t)l * 4096 + k * 64 + h * 16 + d] * atte[l * 64 + h * 16 + d];
    wE[t] = a;
}

// ---------------- CSR build ----------------
__global__ __launch_bounds__(256) void k_hist(const int* __restrict__ dst, int* __restrict__ deg) {
    int e = blockIdx.x * 256 + threadIdx.x;
    if (e < NE) atomicAdd(&deg[dst[e]], 1);
}

__global__ __launch_bounds__(256) void k_chunksum(const int* __restrict__ deg, int* __restrict__ psum) {
    __shared__ int ls[256];
    int i = blockIdx.x * 512 + threadIdx.x;
    int v = 0;
    if (i < NN) v = deg[i];
    if (i + 256 < NN) v += deg[i + 256];
    ls[threadIdx.x] = v;
    __syncthreads();
    for (int st = 128; st; st >>= 1) {
        if ((int)threadIdx.x < st) ls[threadIdx.x] += ls[threadIdx.x + st];
        __syncthreads();
    }
    if (threadIdx.x == 0) psum[blockIdx.x] = ls[0];
}

__global__ __launch_bounds__(256) void k_scantop(int* __restrict__ psum, int nchunk, int* __restrict__ rowp) {
    __shared__ int ls[256];
    int t = threadIdx.x;
    int v = (t < nchunk) ? psum[t] : 0;
    ls[t] = v;
    __syncthreads();
    for (int st = 1; st < 256; st <<= 1) {
        int a = (t >= st) ? ls[t - st] : 0;
        __syncthreads();
        ls[t] += a;
        __syncthreads();
    }
    if (t < nchunk) psum[t] = ls[t] - v;
    if (t == 255) rowp[NN] = ls[255];
}

__global__ __launch_bounds__(512) void k_scanwrite(const int* __restrict__ deg, const int* __restrict__ psum,
                                                   int* __restrict__ rowp) {
    __shared__ int ls[512];
    int i = blockIdx.x * 512 + threadIdx.x;
    int v = (i < NN) ? deg[i] : 0;
    ls[threadIdx.x] = v;
    __syncthreads();
    for (int st = 1; st < 512; st <<= 1) {
        int a = ((int)threadIdx.x >= st) ? ls[threadIdx.x - st] : 0;
        __syncthreads();
        ls[threadIdx.x] += a;
        __syncthreads();
    }
    if (i < NN) rowp[i] = psum[blockIdx.x] + ls[threadIdx.x] - v;
}

__global__ __launch_bounds__(256) void k_scatter(const int* __restrict__ src, const int* __restrict__ dst,
                                                 int* __restrict__ cursor, int* __restrict__ srcS,
                                                 int* __restrict__ eord) {
    int e = blockIdx.x * 256 + threadIdx.x;
    if (e >= NE) return;
    int d = dst[e];
    int p = atomicAdd(&cursor[d], 1);
    srcS[p] = src[e];
    eord[p] = e;
}

// ---------------- edge precompute (CSR order: gather ea, write coalesced) ----------------
__global__ __launch_bounds__(256) void k_edgepre(const float* __restrict__ ea, const float* __restrict__ We,
                                                 const float* __restrict__ be, const float* __restrict__ att,
                                                 const float* __restrict__ wE, const int* __restrict__ eord,
                                                 float* __restrict__ heatt, float4* __restrict__ aed) {
    int p = blockIdx.x * 256 + threadIdx.x;
    if (p >= NE) return;
    int e = eord[p];
    const float4* eav = (const float4*)(ea + (size_t)e * 16);
    float4 A0 = eav[0], A1 = eav[1], A2 = eav[2], A3 = eav[3];
    float a[16] = {A0.x, A0.y, A0.z, A0.w, A1.x, A1.y, A1.z, A1.w,
                   A2.x, A2.y, A2.z, A2.w, A3.x, A3.y, A3.z, A3.w};
    float he[64];
#pragma unroll
    for (int j = 0; j < 64; j++) he[j] = be[j];
#pragma unroll
    for (int k = 0; k < 16; k++) {
        float s = a[k];
#pragma unroll
        for (int j = 0; j < 64; j++) he[j] += s * We[k * 64 + j];
    }
    float hatt = 0.f;
#pragma unroll
    for (int j = 0; j < 64; j++) hatt += he[j] * att[j];
#pragma unroll
    for (int j = 0; j < 64; j++) he[j] = fmaxf(he[j], 0.f);
    heatt[p] = hatt;
#pragma unroll
    for (int l = 0; l < 3; l++) {
        float s0 = 0.f, s1 = 0.f, s2 = 0.f, s3 = 0.f;
#pragma unroll
        for (int j = 0; j < 64; j++) {
            float r = he[j];
            s0 += r * wE[(l * 4 + 0) * 64 + j];
            s1 += r * wE[(l * 4 + 1) * 64 + j];
            s2 += r * wE[(l * 4 + 2) * 64 + j];
            s3 += r * wE[(l * 4 + 3) * 64 + j];
        }
        float4 o; o.x = s0; o.y = s1; o.z = s2; o.w = s3;
        aed[(size_t)l * NE + p] = o;
    }
}

// ---------------- EGAT aggregation: 1 gather pass (online softmax), logits stored in-place ----------------
__global__ __launch_bounds__(64) void k_egat_agg(const int* __restrict__ rowp, const int* __restrict__ srcS,
                                                 float* __restrict__ heatt, const float* __restrict__ hs,
                                                 const float* __restrict__ h, float* __restrict__ xout) {
    int n = blockIdx.x;
    int lane = threadIdx.x;
    int beg = rowp[n], deg = rowp[n + 1] - beg;
    if (deg == 0) { xout[(size_t)n * 64 + lane] = 0.f; return; }
    float hsn = hs[n];
    float m = MNEG, sm = 0.f;
    for (int i = lane; i < deg; i += 64) {
        int s = srcS[beg + i];
        float lg = hs[s] + hsn + heatt[beg + i];
        lg = lg > 0.f ? lg : NEG * lg;
        heatt[beg + i] = lg;                 // store logit (coalesced, in-place)
        float mn = fmaxf(m, lg);
        sm = sm * __expf(m - mn) + __expf(lg - mn);
        m = mn;
    }
#pragma unroll
    for (int o = 32; o; o >>= 1) {
        float mo = __shfl_xor(m, o), so = __shfl_xor(sm, o);
        float mn = fmaxf(m, mo);
        sm = sm * __expf(m - mn) + so * __expf(mo - mn);
        m = mn;
    }
    float inv = 1.f / sm;
    __shared__ float pl[64];
    __shared__ int sl[64];
    float acc = 0.f;
    for (int base = 0; base < deg; base += 64) {
        int i = base + lane;
        if (i < deg) {
            pl[lane] = __expf(heatt[beg + i] - m) * inv;
            sl[lane] = srcS[beg + i];
        }
        __syncthreads();
        int mm = min(64, deg - base);
        int j = 0;
        for (; j + 4 <= mm; j += 4) {
            acc += pl[j] * h[(size_t)sl[j] * 64 + lane];
            acc += pl[j + 1] * h[(size_t)sl[j + 1] * 64 + lane];
            acc += pl[j + 2] * h[(size_t)sl[j + 2] * 64 + lane];
            acc += pl[j + 3] * h[(size_t)sl[j + 3] * 64 + lane];
        }
        for (; j < mm; j++) acc += pl[j] * h[(size_t)sl[j] * 64 + lane];
        __syncthreads();
    }
    xout[(size_t)n * 64 + lane] = fmaxf(acc, 0.f);
}

// ---------------- conv (GATConv) aggregation, 4 heads, 1 gather pass ----------------
__global__ __launch_bounds__(64) void k_conv_agg(const int* __restrict__ rowp, const int* __restrict__ srcS,
                                                 float4* __restrict__ aed, const float* __restrict__ asrc,
                                                 const float* __restrict__ adst, const float* __restrict__ hh,
                                                 const float* __restrict__ bias, float* __restrict__ xout) {
    int n = blockIdx.x;
    int lane = threadIdx.x;
    int beg = rowp[n], deg = rowp[n + 1] - beg;
    if (deg == 0) { xout[(size_t)n * 64 + lane] = fmaxf(bias[lane], 0.f); return; }
    float4 an = ((const float4*)adst)[n];
    float m0 = MNEG, m1 = MNEG, m2 = MNEG, m3 = MNEG;
    float s0 = 0.f, s1 = 0.f, s2 = 0.f, s3 = 0.f;
    for (int i = lane; i < deg; i += 64) {
        int s = srcS[beg + i];
        float4 as4 = ((const float4*)asrc)[s];
        float4 ae = aed[beg + i];
        float l0 = as4.x + an.x + ae.x; l0 = l0 > 0.f ? l0 : NEG * l0;
        float l1 = as4.y + an.y + ae.y; l1 = l1 > 0.f ? l1 : NEG * l1;
        float l2 = as4.z + an.z + ae.z; l2 = l2 > 0.f ? l2 : NEG * l2;
        float l3 = as4.w + an.w + ae.w; l3 = l3 > 0.f ? l3 : NEG * l3;
        float4 o; o.x = l0; o.y = l1; o.z = l2; o.w = l3;
        aed[beg + i] = o;                    // store logits (coalesced, in-place)
        float n0 = fmaxf(m0, l0); s0 = s0 * __expf(m0 - n0) + __expf(l0 - n0); m0 = n0;
        float n1 = fmaxf(m1, l1); s1 = s1 * __expf(m1 - n1) + __expf(l1 - n1); m1 = n1;
        float n2 = fmaxf(m2, l2); s2 = s2 * __expf(m2 - n2) + __expf(l2 - n2); m2 = n2;
        float n3 = fmaxf(m3, l3); s3 = s3 * __expf(m3 - n3) + __expf(l3 - n3); m3 = n3;
    }
#pragma unroll
    for (int o = 32; o; o >>= 1) {
        float mo, so, mn;
        mo = __shfl_xor(m0, o); so = __shfl_xor(s0, o); mn = fmaxf(m0, mo);
        s0 = s0 * __expf(m0 - mn) + so * __expf(mo - mn); m0 = mn;
        mo = __shfl_xor(m1, o); so = __shfl_xor(s1, o); mn = fmaxf(m1, mo);
        s1 = s1 * __expf(m1 - mn) + so * __expf(mo - mn); m1 = mn;
        mo = __shfl_xor(m2, o); so = __shfl_xor(s2, o); mn = fmaxf(m2, mo);
        s2 = s2 * __expf(m2 - mn) + so * __expf(mo - mn); m2 = mn;
        mo = __shfl_xor(m3, o); so = __shfl_xor(s3, o); mn = fmaxf(m3, mo);
        s3 = s3 * __expf(m3 - mn) + so * __expf(mo - mn); m3 = mn;
    }
    float i0 = 1.f / s0, i1 = 1.f / s1, i2 = 1.f / s2, i3 = 1.f / s3;
    __shared__ float pls[4 * 65];
    __shared__ int sl[64];
    float acc = 0.f;
    int hq = lane >> 4;
    for (int base = 0; base < deg; base += 64) {
        int i = base + lane;
        if (i < deg) {
            float4 l4 = aed[beg + i];
            pls[0 * 65 + lane] = __expf(l4.x - m0) * i0;
            pls[1 * 65 + lane] = __expf(l4.y - m1) * i1;
            pls[2 * 65 + lane] = __expf(l4.z - m2) * i2;
            pls[3 * 65 + lane] = __expf(l4.w - m3) * i3;
            sl[lane] = srcS[beg + i];
        }
        __syncthreads();
        int mm = min(64, deg - base);
        const float* prow = &pls[hq * 65];
        int j = 0;
        for (; j + 4 <= mm; j += 4) {
            acc += prow[j] * hh[(size_t)sl[j] * 64 + lane];
            acc += prow[j + 1] * hh[(size_t)sl[j + 1] * 64 + lane];
            acc += prow[j + 2] * hh[(size_t)sl[j + 2] * 64 + lane];
            acc += prow[j + 3] * hh[(size_t)sl[j + 3] * 64 + lane];
        }
        for (; j < mm; j++) acc += prow[j] * hh[(size_t)sl[j] * 64 + lane];
        __syncthreads();
    }
    xout[(size_t)n * 64 + lane] = fmaxf(acc + bias[lane], 0.f);
}

// ---------------- pool + head ----------------
__device__ __forceinline__ int lowerb(const int* a, int n, int key) {
    int lo = 0, hi = n;
    while (lo < hi) {
        int mid = (lo + hi) >> 1;
        if (a[mid] < key) lo = mid + 1; else hi = mid;
    }
    return lo;
}

__global__ __launch_bounds__(256) void k_pool(const float* __restrict__ x, const int* __restrict__ batch,
                                              float* __restrict__ g) {
    int gr = blockIdx.x;
    int lane = threadIdx.x & 63;
    int sub = threadIdx.x >> 6;
    int beg = lowerb(batch, NN, gr);
    int end = lowerb(batch, NN, gr + 1);
    float acc = 0.f;
    for (int i = beg + sub; i < end; i += 4) acc += x[(size_t)i * 64 + lane];
    __shared__ float ls[4][64];
    ls[sub][lane] = acc;
    __syncthreads();
    if (sub == 0)
        g[(size_t)gr * 64 + lane] = ls[0][lane] + ls[1][lane] + ls[2][lane] + ls[3][lane];
}

__global__ __launch_bounds__(64) void k_cls(const float* __restrict__ y, const float* __restrict__ W,
                                            const float* __restrict__ sc, const float* __restrict__ badj,
                                            float* __restrict__ out) {
    int r = blockIdx.x, lane = threadIdx.x;
    __shared__ float yr[64];
    yr[lane] = y[(size_t)r * 64 + lane] * sc[lane];
    __syncthreads();
    float lg = -INFINITY;
    if (lane < NCLS) {
        float a = badj[lane];
        for (int k = 0; k < 64; k++) a += yr[k] * W[k * NCLS + lane];
        lg = a;
    }
    float mx = lg;
#pragma unroll
    for (int o = 32; o; o >>= 1) mx = fmaxf(mx, __shfl_xor(mx, o));
    float e = (lane < NCLS) ? expf(lg - mx) : 0.f;
    float s = e;
#pragma unroll
    for (int o = 32; o; o >>= 1) s += __shfl_xor(s, o);
    if (lane < NCLS) out[(size_t)r * NCLS + lane] = lg - mx - logf(s);
}

extern "C" void kernel_launch(void* const* d_in, const int* in_sizes, int n_in,
                              void* d_out, int out_size, void* d_ws, size_t ws_size,
                              hipStream_t stream) {
    const float* x0  = (const float*)d_in[0];
    const float* ea  = (const float*)d_in[1];
    const int* eidx  = (const int*)d_in[2];
    const int* batch = (const int*)d_in[3];
    const float* Wx  = (const float*)d_in[4];
    const float* bx  = (const float*)d_in[5];
    const float* Wee = (const float*)d_in[6];
    const float* bee = (const float*)d_in[7];
    const float* att = (const float*)d_in[8];
    const float* cW  = (const float*)d_in[9];
    const float* cWe = (const float*)d_in[10];
    const float* cas = (const float*)d_in[11];
    const float* cad = (const float*)d_in[12];
    const float* cae = (const float*)d_in[13];
    const float* cb  = (const float*)d_in[14];
    const float* lW  = (const float*)d_in[15];
    const float* lb  = (const float*)d_in[16];
    const float* clW = (const float*)d_in[17];
    const float* clb = (const float*)d_in[18];
    float* out = (float*)d_out;

    const int* srcA = eidx;
    const int* dstA = eidx + NE;

    char* w = (char*)d_ws;
    size_t off = 0;
    auto alloc = [&](size_t bytes) -> void* {
        void* p = w + off;
        off += (bytes + 255) & ~(size_t)255;
        return p;
    };
    float* A      = (float*)alloc((size_t)NN * 64 * 4);
    float* B      = (float*)alloc((size_t)NN * 64 * 4);
    float* hs     = (float*)alloc((size_t)NN * 4);
    float* asrc   = (float*)alloc((size_t)NN * 4 * 4);
    float* adst   = (float*)alloc((size_t)NN * 4 * 4);
    float* heatt  = (float*)alloc((size_t)NE * 4);
    float4* aed   = (float4*)alloc((size_t)3 * NE * 16);
    int* srcS     = (int*)alloc((size_t)NE * 4);
    int* eord     = (int*)alloc((size_t)NE * 4);
    int* rowp     = (int*)alloc((size_t)(NN + 1) * 4);
    int* deg      = (int*)alloc((size_t)NN * 4);
    int* cursor   = (int*)alloc((size_t)NN * 4);
    int* psum     = (int*)alloc(4096);
    float* part   = (float*)alloc((size_t)2 * 200 * 64 * 4);
    float* sc     = (float*)alloc(64 * 4);
    float* sh     = (float*)alloc(64 * 4);
    float* badj   = (float*)alloc(64 * 4);
    float* wE     = (float*)alloc(768 * 4);
    float* g      = (float*)alloc((size_t)NG * 64 * 4);
    float* y      = (float*)alloc((size_t)NG * 64 * 4);
    float* badj2  = (float*)alloc(64 * 4);
    float* badj3  = (float*)alloc(64 * 4);
    if (off > ws_size) return;

    const int NB = 200;
    const int NCHUNK = (NN + 511) / 512;  // 196

    // ---- CSR build (by dst) ----
    hipMemsetAsync(deg, 0, (size_t)NN * 4, stream);
    k_hist<<<(NE + 255) / 256, 256, 0, stream>>>(dstA, deg);
    k_chunksum<<<NCHUNK, 256, 0, stream>>>(deg, psum);
    k_scantop<<<1, 256, 0, stream>>>(psum, NCHUNK, rowp);
    k_scanwrite<<<NCHUNK, 512, 0, stream>>>(deg, psum, rowp);
    hipMemcpyAsync(cursor, rowp, (size_t)NN * 4, hipMemcpyDeviceToDevice, stream);
    k_scatter<<<(NE + 255) / 256, 256, 0, stream>>>(srcA, dstA, cursor, srcS, eord);

    // ---- folded edge-attention weights ----
    k_we<<<1, 768, 0, stream>>>(cWe, cae, wE);

    // ---- BN(x0) folded into EGAT node GEMM: A = h (+ fused hs epilogue) ----
    k_bn_part<32><<<NB, 256, 0, stream>>>(x0, NN, part);
    k_bn_final<<<1, 64, 0, stream>>>(part, NB, NN, 32, sc, sh);
    k_adjbias<<<1, 64, 0, stream>>>(sh, Wx, bx, 32, 64, badj);
    k_gemm_bn<32, false, 1><<<(NN + 31) / 32, 256, 0, stream>>>(
        x0, Wx, sc, badj, A, NN, att, hs, nullptr, nullptr, nullptr, nullptr);

    // ---- edge precompute (CSR order, coalesced writes) ----
    k_edgepre<<<(NE + 255) / 256, 256, 0, stream>>>(ea, Wee, bee, att, wE, eord, heatt, aed);

    // ---- EGAT aggregation ----
    k_egat_agg<<<NN, 64, 0, stream>>>(rowp, srcS, heatt, hs, A, B);

    // ---- 3 GATConv layers ----
    for (int l = 0; l < 3; l++) {
        k_bn_part<64><<<NB, 256, 0, stream>>>(B, NN, part);
        k_bn_final<<<1, 64, 0, stream>>>(part, NB, NN, 64, sc, sh);
        k_adjbias<<<1, 64, 0, stream>>>(sh, cW + (size_t)l * 4096, nullptr, 64, 64, badj);
        k_gemm_bn<64, false, 2><<<(NN + 31) / 32, 256, 0, stream>>>(
            B, cW + (size_t)l * 4096, sc, badj, A, NN,
            nullptr, nullptr, cas + l * 64, cad + l * 64, asrc, adst);
        k_conv_agg<<<NN, 64, 0, stream>>>(rowp, srcS, aed + (size_t)l * NE, asrc, adst, A,
                                          cb + l * 64, B);
    }

    // ---- global add pool ----
    k_pool<<<NG, 256, 0, stream>>>(B, batch, g);

    // ---- head ----
    k_bn_part<64><<<2, 256, 0, stream>>>(g, NG, part);
    k_bn_final<<<1, 64, 0, stream>>>(part, 2, NG, 64, sc, sh);
    k_adjbias<<<1, 64, 0, stream>>>(sh, lW, lb, 64, 64, badj2);
    k_gemm_bn<64, true, 0><<<(NG + 31) / 32, 256, 0, stream>>>(
        g, lW, sc, badj2, y, NG, nullptr, nullptr, nullptr, nullptr, nullptr, nullptr);

    k_bn_part<64><<<2, 256, 0, stream>>>(y, NG, part);
    k_bn_final<<<1, 64, 0, stream>>>(part, 2, NG, 64, sc, sh);
    k_adjbias<<<1, 64, 0, stream>>>(sh, clW, clb, 64, 10, badj3);
    k_cls<<<NG, 64, 0, stream>>>(y, clW, sc, badj3, out);
}

// Round 3
// 1175.764 us; speedup vs baseline: 1.1903x; 1.1281x over previous
//
#include <hip/hip_runtime.h>
#include <math.h>

#define NN 100000
#define NE 1600000
#define NG 512
#define NCLS 10
#define NEG 0.2f
#define BNEPS 1e-5f
#define BNB 1e-4f
#define MNEG -1e30f

typedef unsigned short u16;
typedef unsigned int u32;

__device__ __forceinline__ u16 f2bf(float x) {
    u32 u = __float_as_uint(x);
    u32 r = (u + 0x7fffu + ((u >> 16) & 1u)) >> 16;
    return (u16)r;
}
__device__ __forceinline__ float bf2f(u16 s) { return __uint_as_float(((u32)s) << 16); }

// ---------------- BatchNorm stats (two-stage, deterministic) ----------------
template<int C>
__global__ __launch_bounds__(256) void k_bn_part(const float* __restrict__ x, int rows,
                                                 float* __restrict__ part) {
    const int RPI = 256 / C;
    int col = threadIdx.x % C;
    int sub = threadIdx.x / C;
    int nb = gridDim.x;
    int rpb = (rows + nb - 1) / nb;
    int r0 = blockIdx.x * rpb;
    int r1 = min(rows, r0 + rpb);
    float s = 0.f, q = 0.f;
    for (int r = r0 + sub; r < r1; r += RPI) {
        float v = x[(size_t)r * C + col];
        s += v; q += v * v;
    }
    __shared__ float ls[256], lq[256];
    ls[threadIdx.x] = s; lq[threadIdx.x] = q;
    __syncthreads();
    for (int st = RPI / 2; st > 0; st >>= 1) {
        if (sub < st) {
            ls[threadIdx.x] += ls[threadIdx.x + st * C];
            lq[threadIdx.x] += lq[threadIdx.x + st * C];
        }
        __syncthreads();
    }
    if (sub == 0) {
        part[(size_t)blockIdx.x * C + col] = ls[col];
        part[(size_t)(nb + blockIdx.x) * C + col] = lq[col];
    }
}

// fused: BN final stats + adjusted bias  badj[j] = b[j] + sum_k sh[k]*W[k][j]
__global__ __launch_bounds__(64) void k_bn_adj(const float* __restrict__ part, int nb, int rows, int C,
                                               const float* __restrict__ W, const float* __restrict__ b,
                                               int Ncol, float* __restrict__ sc, float* __restrict__ badj) {
    int c = threadIdx.x;
    __shared__ float shl[64];
    if (c < C) {
        float s = 0.f, q = 0.f;
        for (int bb = 0; bb < nb; bb++) {
            s += part[(size_t)bb * C + c];
            q += part[(size_t)(nb + bb) * C + c];
        }
        float mu = s / rows;
        float var = q / rows - mu * mu;
        float sl = rsqrtf(var + BNEPS);
        sc[c] = sl;
        shl[c] = BNB - mu * sl;
    }
    __syncthreads();
    if (c < Ncol) {
        float a = b ? b[c] : 0.f;
        for (int k = 0; k < C; k++) a += shl[k] * W[(size_t)k * Ncol + c];
        badj[c] = a;
    }
}

// out[r][j] = (x[r]*sc) @ W + badj[j]. W is [K][64]. OBF: write bf16 table.
// EPI=1: hs[r] = out_row . att ; EPI=2: asrc/adst per-head dots.
template<int K, int EPI, bool RELU, bool OBF>
__global__ __launch_bounds__(256) void k_gemm_bn(const float* __restrict__ x, const float* __restrict__ W,
                                                 const float* __restrict__ sc, const float* __restrict__ badj,
                                                 float* __restrict__ outf, u16* __restrict__ outb, int rows,
                                                 const float* __restrict__ att, float* __restrict__ hs,
                                                 const float* __restrict__ as_, const float* __restrict__ ad_,
                                                 float* __restrict__ asrc, float* __restrict__ adst) {
    __shared__ float Ws[K * 64];
    __shared__ float Xs[32 * K];
    int r0 = blockIdx.x * 32;
    for (int i = threadIdx.x; i < K * 64; i += 256) Ws[i] = W[i];
    for (int i = threadIdx.x; i < 32 * K; i += 256) {
        int r = r0 + i / K, k = i % K;
        Xs[i] = (r < rows) ? x[(size_t)r * K + k] * sc[k] : 0.f;
    }
    __syncthreads();
    int col = threadIdx.x & 63;
    int rg = threadIdx.x >> 6;
    float b0 = badj[col];
    float acc[8];
#pragma unroll
    for (int i = 0; i < 8; i++) acc[i] = b0;
    for (int k = 0; k < K; k++) {
        float w = Ws[k * 64 + col];
#pragma unroll
        for (int i = 0; i < 8; i++) acc[i] += Xs[(rg * 8 + i) * K + k] * w;
    }
#pragma unroll
    for (int i = 0; i < 8; i++) {
        int r = r0 + rg * 8 + i;
        if (r < rows) {
            float v = RELU ? fmaxf(acc[i], 0.f) : acc[i];
            if (OBF) outb[(size_t)r * 64 + col] = f2bf(v);
            else     outf[(size_t)r * 64 + col] = v;
        }
    }
    if (EPI == 1) {
        float a = att[col];
#pragma unroll
        for (int i = 0; i < 8; i++) {
            float v = acc[i] * a;
#pragma unroll
            for (int o = 32; o; o >>= 1) v += __shfl_xor(v, o);
            int r = r0 + rg * 8 + i;
            if (col == 0 && r < rows) hs[r] = v;
        }
    }
    if (EPI == 2) {
        float a1 = as_[col], a2 = ad_[col];
#pragma unroll
        for (int i = 0; i < 8; i++) {
            float s1 = acc[i] * a1, s2 = acc[i] * a2;
#pragma unroll
            for (int o = 1; o < 16; o <<= 1) { s1 += __shfl_xor(s1, o); s2 += __shfl_xor(s2, o); }
            int r = r0 + rg * 8 + i;
            if ((col & 15) == 0 && r < rows) {
                asrc[(size_t)r * 4 + (col >> 4)] = s1;
                adst[(size_t)r * 4 + (col >> 4)] = s2;
            }
        }
    }
}

// wEbuf[0..767]: wE[l][h][k] = sum_d cWe[l][k][h*16+d]*cae[l][h][d]
// wEbuf[768..783]: vatt[k] = sum_j Wee[k][j]*att[j] ;  wEbuf[784] = be.att
__global__ __launch_bounds__(768) void k_we(const float* __restrict__ cWe, const float* __restrict__ cae,
                                            const float* __restrict__ Wee, const float* __restrict__ att,
                                            const float* __restrict__ bee, float* __restrict__ wEbuf) {
    int t = threadIdx.x;
    int l = t >> 8;
    int h = (t >> 6) & 3;
    int k = t & 63;
    float a = 0.f;
    for (int d = 0; d < 16; d++)
        a += cWe[(size_t)l * 4096 + k * 64 + h * 16 + d] * cae[l * 64 + h * 16 + d];
    wEbuf[t] = a;
    if (t < 16) {
        float v = 0.f;
        for (int j = 0; j < 64; j++) v += Wee[t * 64 + j] * att[j];
        wEbuf[768 + t] = v;
    }
    if (t == 16) {
        float v = 0.f;
        for (int j = 0; j < 64; j++) v += bee[j] * att[j];
        wEbuf[784] = v;
    }
}

// ---------------- CSR build ----------------
__global__ __launch_bounds__(256) void k_hist(const int* __restrict__ dst, int* __restrict__ deg) {
    int e = blockIdx.x * 256 + threadIdx.x;
    if (e < NE) atomicAdd(&deg[dst[e]], 1);
}

__global__ __launch_bounds__(256) void k_chunksum(const int* __restrict__ deg, int* __restrict__ psum) {
    __shared__ int ls[256];
    int i = blockIdx.x * 512 + threadIdx.x;
    int v = 0;
    if (i < NN) v = deg[i];
    if (i + 256 < NN) v += deg[i + 256];
    ls[threadIdx.x] = v;
    __syncthreads();
    for (int st = 128; st; st >>= 1) {
        if ((int)threadIdx.x < st) ls[threadIdx.x] += ls[threadIdx.x + st];
        __syncthreads();
    }
    if (threadIdx.x == 0) psum[blockIdx.x] = ls[0];
}

__global__ __launch_bounds__(256) void k_scantop(int* __restrict__ psum, int nchunk, int* __restrict__ rowp) {
    __shared__ int ls[256];
    int t = threadIdx.x;
    int v = (t < nchunk) ? psum[t] : 0;
    ls[t] = v;
    __syncthreads();
    for (int st = 1; st < 256; st <<= 1) {
        int a = (t >= st) ? ls[t - st] : 0;
        __syncthreads();
        ls[t] += a;
        __syncthreads();
    }
    if (t < nchunk) psum[t] = ls[t] - v;
    if (t == 255) rowp[NN] = ls[255];
}

__global__ __launch_bounds__(512) void k_scanwrite(const int* __restrict__ deg, const int* __restrict__ psum,
                                                   int* __restrict__ rowp) {
    __shared__ int ls[512];
    int i = blockIdx.x * 512 + threadIdx.x;
    int v = (i < NN) ? deg[i] : 0;
    ls[threadIdx.x] = v;
    __syncthreads();
    for (int st = 1; st < 512; st <<= 1) {
        int a = ((int)threadIdx.x >= st) ? ls[threadIdx.x - st] : 0;
        __syncthreads();
        ls[threadIdx.x] += a;
        __syncthreads();
    }
    if (i < NN) rowp[i] = psum[blockIdx.x] + ls[threadIdx.x] - v;
}

__global__ __launch_bounds__(256) void k_scatter(const int* __restrict__ src, const int* __restrict__ dst,
                                                 int* __restrict__ cursor, int2* __restrict__ se) {
    int e = blockIdx.x * 256 + threadIdx.x;
    if (e >= NE) return;
    int d = dst[e];
    int p = atomicAdd(&cursor[d], 1);
    int2 v; v.x = src[e]; v.y = e;
    se[p] = v;
}

// ---------------- edge precompute (CSR order; float2-packed math) ----------------
__global__ __launch_bounds__(256) void k_edgepre(const float* __restrict__ ea, const float* __restrict__ Wee,
                                                 const float* __restrict__ bee, const float* __restrict__ wEbuf,
                                                 const int2* __restrict__ se,
                                                 float* __restrict__ heatt, float4* __restrict__ aed) {
    int p = blockIdx.x * 256 + threadIdx.x;
    if (p >= NE) return;
    int e = se[p].y;
    const float4* eav = (const float4*)(ea + (size_t)e * 16);
    float4 A0 = eav[0], A1 = eav[1], A2 = eav[2], A3 = eav[3];
    float a[16] = {A0.x, A0.y, A0.z, A0.w, A1.x, A1.y, A1.z, A1.w,
                   A2.x, A2.y, A2.z, A2.w, A3.x, A3.y, A3.z, A3.w};
    // hatt = a . vatt + be.att   (algebraic fold)
    float hatt = wEbuf[784];
#pragma unroll
    for (int k = 0; k < 16; k++) hatt = fmaf(a[k], wEbuf[768 + k], hatt);
    heatt[p] = hatt;
    // he = a @ We + be (packed float2)
    const float2* We2 = (const float2*)Wee;
    const float2* be2 = (const float2*)bee;
    float2 he[32];
#pragma unroll
    for (int j = 0; j < 32; j++) he[j] = be2[j];
#pragma unroll
    for (int k = 0; k < 16; k++) {
        float s = a[k];
#pragma unroll
        for (int j = 0; j < 32; j++) {
            float2 w = We2[k * 32 + j];
            he[j].x = fmaf(s, w.x, he[j].x);
            he[j].y = fmaf(s, w.y, he[j].y);
        }
    }
#pragma unroll
    for (int j = 0; j < 32; j++) {
        he[j].x = fmaxf(he[j].x, 0.f);
        he[j].y = fmaxf(he[j].y, 0.f);
    }
#pragma unroll
    for (int l = 0; l < 3; l++) {
        const float2* w0 = (const float2*)(wEbuf + (l * 4 + 0) * 64);
        const float2* w1 = (const float2*)(wEbuf + (l * 4 + 1) * 64);
        const float2* w2 = (const float2*)(wEbuf + (l * 4 + 2) * 64);
        const float2* w3 = (const float2*)(wEbuf + (l * 4 + 3) * 64);
        float s0 = 0.f, s1 = 0.f, s2 = 0.f, s3 = 0.f;
#pragma unroll
        for (int j = 0; j < 32; j++) {
            float2 r = he[j];
            float2 a0 = w0[j], a1 = w1[j], a2 = w2[j], a3 = w3[j];
            s0 += r.x * a0.x + r.y * a0.y;
            s1 += r.x * a1.x + r.y * a1.y;
            s2 += r.x * a2.x + r.y * a2.y;
            s3 += r.x * a3.x + r.y * a3.y;
        }
        float4 o; o.x = s0; o.y = s1; o.z = s2; o.w = s3;
        aed[(size_t)l * NE + p] = o;
    }
}

// ---------------- EGAT aggregation ----------------
__global__ __launch_bounds__(64) void k_egat_agg(const int* __restrict__ rowp, const int2* __restrict__ se,
                                                 float* __restrict__ heatt, const float* __restrict__ hs,
                                                 const u16* __restrict__ hb, float* __restrict__ xout) {
    int n = blockIdx.x;
    int lane = threadIdx.x;
    int beg = rowp[n], deg = rowp[n + 1] - beg;
    float hsn = hs[n];
    __shared__ float pl[64];
    __shared__ int sl[64];
    if (deg <= 64) {
        float lg = MNEG;
        int s = 0;
        if (lane < deg) {
            s = se[beg + lane].x;
            lg = hs[s] + hsn + heatt[beg + lane];
            lg = lg > 0.f ? lg : NEG * lg;
        }
        float m = lg;
#pragma unroll
        for (int o = 32; o; o >>= 1) m = fmaxf(m, __shfl_xor(m, o));
        float e = (lane < deg) ? __expf(lg - m) : 0.f;
        float sm = e;
#pragma unroll
        for (int o = 32; o; o >>= 1) sm += __shfl_xor(sm, o);
        float inv = sm > 0.f ? 1.f / sm : 0.f;
        pl[lane] = e * inv;
        sl[lane] = s;
        __syncthreads();
        float acc = 0.f;
        int j = 0;
        for (; j + 4 <= deg; j += 4) {
            acc = fmaf(pl[j],     bf2f(hb[(size_t)sl[j]     * 64 + lane]), acc);
            acc = fmaf(pl[j + 1], bf2f(hb[(size_t)sl[j + 1] * 64 + lane]), acc);
            acc = fmaf(pl[j + 2], bf2f(hb[(size_t)sl[j + 2] * 64 + lane]), acc);
            acc = fmaf(pl[j + 3], bf2f(hb[(size_t)sl[j + 3] * 64 + lane]), acc);
        }
        for (; j < deg; j++) acc = fmaf(pl[j], bf2f(hb[(size_t)sl[j] * 64 + lane]), acc);
        xout[(size_t)n * 64 + lane] = fmaxf(acc, 0.f);
        return;
    }
    // fallback: two-pass online softmax with in-place logit store
    float m = MNEG, sm = 0.f;
    for (int i = lane; i < deg; i += 64) {
        int s = se[beg + i].x;
        float lg = hs[s] + hsn + heatt[beg + i];
        lg = lg > 0.f ? lg : NEG * lg;
        heatt[beg + i] = lg;
        float mn = fmaxf(m, lg);
        sm = sm * __expf(m - mn) + __expf(lg - mn);
        m = mn;
    }
#pragma unroll
    for (int o = 32; o; o >>= 1) {
        float mo = __shfl_xor(m, o), so = __shfl_xor(sm, o);
        float mn = fmaxf(m, mo);
        sm = sm * __expf(m - mn) + so * __expf(mo - mn);
        m = mn;
    }
    float inv = 1.f / sm;
    float acc = 0.f;
    for (int base = 0; base < deg; base += 64) {
        int i = base + lane;
        if (i < deg) {
            pl[lane] = __expf(heatt[beg + i] - m) * inv;
            sl[lane] = se[beg + i].x;
        }
        __syncthreads();
        int mm = min(64, deg - base);
        for (int j = 0; j < mm; j++)
            acc = fmaf(pl[j], bf2f(hb[(size_t)sl[j] * 64 + lane]), acc);
        __syncthreads();
    }
    xout[(size_t)n * 64 + lane] = fmaxf(acc, 0.f);
}

// ---------------- conv (GATConv) aggregation, 4 heads ----------------
__global__ __launch_bounds__(64) void k_conv_agg(const int* __restrict__ rowp, const int2* __restrict__ se,
                                                 float4* __restrict__ aed, const float* __restrict__ asrc,
                                                 const float* __restrict__ adst, const u16* __restrict__ hb,
                                                 const float* __restrict__ bias, float* __restrict__ xout) {
    int n = blockIdx.x;
    int lane = threadIdx.x;
    int beg = rowp[n], deg = rowp[n + 1] - beg;
    float4 an = ((const float4*)adst)[n];
    __shared__ float pls[4 * 72];
    __shared__ int sl[64];
    int hq = lane >> 4;
    if (deg <= 64) {
        float l0 = MNEG, l1 = MNEG, l2 = MNEG, l3 = MNEG;
        int s = 0;
        if (lane < deg) {
            s = se[beg + lane].x;
            float4 as4 = ((const float4*)asrc)[s];
            float4 ae = aed[beg + lane];
            l0 = as4.x + an.x + ae.x; l0 = l0 > 0.f ? l0 : NEG * l0;
            l1 = as4.y + an.y + ae.y; l1 = l1 > 0.f ? l1 : NEG * l1;
            l2 = as4.z + an.z + ae.z; l2 = l2 > 0.f ? l2 : NEG * l2;
            l3 = as4.w + an.w + ae.w; l3 = l3 > 0.f ? l3 : NEG * l3;
        }
        float m0 = l0, m1 = l1, m2 = l2, m3 = l3;
#pragma unroll
        for (int o = 32; o; o >>= 1) {
            m0 = fmaxf(m0, __shfl_xor(m0, o)); m1 = fmaxf(m1, __shfl_xor(m1, o));
            m2 = fmaxf(m2, __shfl_xor(m2, o)); m3 = fmaxf(m3, __shfl_xor(m3, o));
        }
        float e0 = (lane < deg) ? __expf(l0 - m0) : 0.f;
        float e1 = (lane < deg) ? __expf(l1 - m1) : 0.f;
        float e2 = (lane < deg) ? __expf(l2 - m2) : 0.f;
        float e3 = (lane < deg) ? __expf(l3 - m3) : 0.f;
        float s0 = e0, s1 = e1, s2 = e2, s3 = e3;
#pragma unroll
        for (int o = 32; o; o >>= 1) {
            s0 += __shfl_xor(s0, o); s1 += __shfl_xor(s1, o);
            s2 += __shfl_xor(s2, o); s3 += __shfl_xor(s3, o);
        }
        float i0 = s0 > 0.f ? 1.f / s0 : 0.f;
        float i1 = s1 > 0.f ? 1.f / s1 : 0.f;
        float i2 = s2 > 0.f ? 1.f / s2 : 0.f;
        float i3 = s3 > 0.f ? 1.f / s3 : 0.f;
        pls[0 * 72 + lane] = e0 * i0;
        pls[1 * 72 + lane] = e1 * i1;
        pls[2 * 72 + lane] = e2 * i2;
        pls[3 * 72 + lane] = e3 * i3;
        sl[lane] = s;
        __syncthreads();
        const float* prow = &pls[hq * 72];
        float acc = 0.f;
        int j = 0;
        for (; j + 4 <= deg; j += 4) {
            acc = fmaf(prow[j],     bf2f(hb[(size_t)sl[j]     * 64 + lane]), acc);
            acc = fmaf(prow[j + 1], bf2f(hb[(size_t)sl[j + 1] * 64 + lane]), acc);
            acc = fmaf(prow[j + 2], bf2f(hb[(size_t)sl[j + 2] * 64 + lane]), acc);
            acc = fmaf(prow[j + 3], bf2f(hb[(size_t)sl[j + 3] * 64 + lane]), acc);
        }
        for (; j < deg; j++) acc = fmaf(prow[j], bf2f(hb[(size_t)sl[j] * 64 + lane]), acc);
        xout[(size_t)n * 64 + lane] = fmaxf(acc + bias[lane], 0.f);
        return;
    }
    // fallback path
    float m0 = MNEG, m1 = MNEG, m2 = MNEG, m3 = MNEG;
    float s0 = 0.f, s1 = 0.f, s2 = 0.f, s3 = 0.f;
    for (int i = lane; i < deg; i += 64) {
        int s = se[beg + i].x;
        float4 as4 = ((const float4*)asrc)[s];
        float4 ae = aed[beg + i];
        float l0 = as4.x + an.x + ae.x; l0 = l0 > 0.f ? l0 : NEG * l0;
        float l1 = as4.y + an.y + ae.y; l1 = l1 > 0.f ? l1 : NEG * l1;
        float l2 = as4.z + an.z + ae.z; l2 = l2 > 0.f ? l2 : NEG * l2;
        float l3 = as4.w + an.w + ae.w; l3 = l3 > 0.f ? l3 : NEG * l3;
        float4 o4; o4.x = l0; o4.y = l1; o4.z = l2; o4.w = l3;
        aed[beg + i] = o4;
        float n0 = fmaxf(m0, l0); s0 = s0 * __expf(m0 - n0) + __expf(l0 - n0); m0 = n0;
        float n1 = fmaxf(m1, l1); s1 = s1 * __expf(m1 - n1) + __expf(l1 - n1); m1 = n1;
        float n2 = fmaxf(m2, l2); s2 = s2 * __expf(m2 - n2) + __expf(l2 - n2); m2 = n2;
        float n3 = fmaxf(m3, l3); s3 = s3 * __expf(m3 - n3) + __expf(l3 - n3); m3 = n3;
    }
#pragma unroll
    for (int o = 32; o; o >>= 1) {
        float mo, so, mn;
        mo = __shfl_xor(m0, o); so = __shfl_xor(s0, o); mn = fmaxf(m0, mo);
        s0 = s0 * __expf(m0 - mn) + so * __expf(mo - mn); m0 = mn;
        mo = __shfl_xor(m1, o); so = __shfl_xor(s1, o); mn = fmaxf(m1, mo);
        s1 = s1 * __expf(m1 - mn) + so * __expf(mo - mn); m1 = mn;
        mo = __shfl_xor(m2, o); so = __shfl_xor(s2, o); mn = fmaxf(m2, mo);
        s2 = s2 * __expf(m2 - mn) + so * __expf(mo - mn); m2 = mn;
        mo = __shfl_xor(m3, o); so = __shfl_xor(s3, o); mn = fmaxf(m3, mo);
        s3 = s3 * __expf(m3 - mn) + so * __expf(mo - mn); m3 = mn;
    }
    float i0 = 1.f / s0, i1 = 1.f / s1, i2 = 1.f / s2, i3 = 1.f / s3;
    float acc = 0.f;
    for (int base = 0; base < deg; base += 64) {
        int i = base + lane;
        if (i < deg) {
            float4 l4 = aed[beg + i];
            pls[0 * 72 + lane] = __expf(l4.x - m0) * i0;
            pls[1 * 72 + lane] = __expf(l4.y - m1) * i1;
            pls[2 * 72 + lane] = __expf(l4.z - m2) * i2;
            pls[3 * 72 + lane] = __expf(l4.w - m3) * i3;
            sl[lane] = se[beg + i].x;
        }
        __syncthreads();
        int mm = min(64, deg - base);
        const float* prow = &pls[hq * 72];
        for (int j = 0; j < mm; j++)
            acc = fmaf(prow[j], bf2f(hb[(size_t)sl[j] * 64 + lane]), acc);
        __syncthreads();
    }
    xout[(size_t)n * 64 + lane] = fmaxf(acc + bias[lane], 0.f);
}

// ---------------- pool + head ----------------
__device__ __forceinline__ int lowerb(const int* a, int n, int key) {
    int lo = 0, hi = n;
    while (lo < hi) {
        int mid = (lo + hi) >> 1;
        if (a[mid] < key) lo = mid + 1; else hi = mid;
    }
    return lo;
}

__global__ __launch_bounds__(256) void k_pool(const float* __restrict__ x, const int* __restrict__ batch,
                                              float* __restrict__ g) {
    int gr = blockIdx.x;
    int lane = threadIdx.x & 63;
    int sub = threadIdx.x >> 6;
    int beg = lowerb(batch, NN, gr);
    int end = lowerb(batch, NN, gr + 1);
    float acc = 0.f;
    for (int i = beg + sub; i < end; i += 4) acc += x[(size_t)i * 64 + lane];
    __shared__ float ls[4][64];
    ls[sub][lane] = acc;
    __syncthreads();
    if (sub == 0)
        g[(size_t)gr * 64 + lane] = ls[0][lane] + ls[1][lane] + ls[2][lane] + ls[3][lane];
}

__global__ __launch_bounds__(64) void k_cls(const float* __restrict__ y, const float* __restrict__ W,
                                            const float* __restrict__ sc, const float* __restrict__ badj,
                                            float* __restrict__ out) {
    int r = blockIdx.x, lane = threadIdx.x;
    __shared__ float yr[64];
    yr[lane] = y[(size_t)r * 64 + lane] * sc[lane];
    __syncthreads();
    float lg = -INFINITY;
    if (lane < NCLS) {
        float a = badj[lane];
        for (int k = 0; k < 64; k++) a += yr[k] * W[k * NCLS + lane];
        lg = a;
    }
    float mx = lg;
#pragma unroll
    for (int o = 32; o; o >>= 1) mx = fmaxf(mx, __shfl_xor(mx, o));
    float e = (lane < NCLS) ? expf(lg - mx) : 0.f;
    float s = e;
#pragma unroll
    for (int o = 32; o; o >>= 1) s += __shfl_xor(s, o);
    if (lane < NCLS) out[(size_t)r * NCLS + lane] = lg - mx - logf(s);
}

extern "C" void kernel_launch(void* const* d_in, const int* in_sizes, int n_in,
                              void* d_out, int out_size, void* d_ws, size_t ws_size,
                              hipStream_t stream) {
    const float* x0  = (const float*)d_in[0];
    const float* ea  = (const float*)d_in[1];
    const int* eidx  = (const int*)d_in[2];
    const int* batch = (const int*)d_in[3];
    const float* Wx  = (const float*)d_in[4];
    const float* bx  = (const float*)d_in[5];
    const float* Wee = (const float*)d_in[6];
    const float* bee = (const float*)d_in[7];
    const float* att = (const float*)d_in[8];
    const float* cW  = (const float*)d_in[9];
    const float* cWe = (const float*)d_in[10];
    const float* cas = (const float*)d_in[11];
    const float* cad = (const float*)d_in[12];
    const float* cae = (const float*)d_in[13];
    const float* cb  = (const float*)d_in[14];
    const float* lW  = (const float*)d_in[15];
    const float* lb  = (const float*)d_in[16];
    const float* clW = (const float*)d_in[17];
    const float* clb = (const float*)d_in[18];
    float* out = (float*)d_out;

    const int* srcA = eidx;
    const int* dstA = eidx + NE;

    char* w = (char*)d_ws;
    size_t off = 0;
    auto alloc = [&](size_t bytes) -> void* {
        void* p = w + off;
        off += (bytes + 255) & ~(size_t)255;
        return p;
    };
    u16* hbA      = (u16*)alloc((size_t)NN * 64 * 2);     // bf16 node-value table
    float* B      = (float*)alloc((size_t)NN * 64 * 4);
    float* hs     = (float*)alloc((size_t)NN * 4);
    float* asrc   = (float*)alloc((size_t)NN * 4 * 4);
    float* adst   = (float*)alloc((size_t)NN * 4 * 4);
    float* heatt  = (float*)alloc((size_t)NE * 4);
    float4* aed   = (float4*)alloc((size_t)3 * NE * 16);
    int2* se      = (int2*)alloc((size_t)NE * 8);
    int* rowp     = (int*)alloc((size_t)(NN + 1) * 4);
    int* deg      = (int*)alloc((size_t)NN * 4);
    int* cursor   = (int*)alloc((size_t)NN * 4);
    int* psum     = (int*)alloc(4096);
    float* part   = (float*)alloc((size_t)2 * 200 * 64 * 4);
    float* sc     = (float*)alloc(64 * 4);
    float* badj   = (float*)alloc(64 * 4);
    float* wEbuf  = (float*)alloc(800 * 4);
    float* g      = (float*)alloc((size_t)NG * 64 * 4);
    float* y      = (float*)alloc((size_t)NG * 64 * 4);
    float* badj2  = (float*)alloc(64 * 4);
    float* badj3  = (float*)alloc(64 * 4);
    float* sc2    = (float*)alloc(64 * 4);
    float* sc3    = (float*)alloc(64 * 4);
    if (off > ws_size) return;

    const int NB = 200;
    const int NCHUNK = (NN + 511) / 512;  // 196

    // ---- CSR build (by dst) ----
    hipMemsetAsync(deg, 0, (size_t)NN * 4, stream);
    k_hist<<<(NE + 255) / 256, 256, 0, stream>>>(dstA, deg);
    k_chunksum<<<NCHUNK, 256, 0, stream>>>(deg, psum);
    k_scantop<<<1, 256, 0, stream>>>(psum, NCHUNK, rowp);
    k_scanwrite<<<NCHUNK, 512, 0, stream>>>(deg, psum, rowp);
    hipMemcpyAsync(cursor, rowp, (size_t)NN * 4, hipMemcpyDeviceToDevice, stream);
    k_scatter<<<(NE + 255) / 256, 256, 0, stream>>>(srcA, dstA, cursor, se);

    // ---- folded attention weights ----
    k_we<<<1, 768, 0, stream>>>(cWe, cae, Wee, att, bee, wEbuf);

    // ---- BN(x0) + EGAT node GEMM -> hbA (bf16) + hs epilogue ----
    k_bn_part<32><<<NB, 256, 0, stream>>>(x0, NN, part);
    k_bn_adj<<<1, 64, 0, stream>>>(part, NB, NN, 32, Wx, bx, 64, sc, badj);
    k_gemm_bn<32, 1, false, true><<<(NN + 31) / 32, 256, 0, stream>>>(
        x0, Wx, sc, badj, nullptr, hbA, NN, att, hs, nullptr, nullptr, nullptr, nullptr);

    // ---- edge precompute ----
    k_edgepre<<<(NE + 255) / 256, 256, 0, stream>>>(ea, Wee, bee, wEbuf, se, heatt, aed);

    // ---- EGAT aggregation -> B ----
    k_egat_agg<<<NN, 64, 0, stream>>>(rowp, se, heatt, hs, hbA, B);

    // ---- 3 GATConv layers ----
    for (int l = 0; l < 3; l++) {
        k_bn_part<64><<<NB, 256, 0, stream>>>(B, NN, part);
        k_bn_adj<<<1, 64, 0, stream>>>(part, NB, NN, 64, cW + (size_t)l * 4096, nullptr, 64, sc, badj);
        k_gemm_bn<64, 2, false, true><<<(NN + 31) / 32, 256, 0, stream>>>(
            B, cW + (size_t)l * 4096, sc, badj, nullptr, hbA, NN,
            nullptr, nullptr, cas + l * 64, cad + l * 64, asrc, adst);
        k_conv_agg<<<NN, 64, 0, stream>>>(rowp, se, aed + (size_t)l * NE, asrc, adst, hbA,
                                          cb + l * 64, B);
    }

    // ---- global add pool ----
    k_pool<<<NG, 256, 0, stream>>>(B, batch, g);

    // ---- head ----
    k_bn_part<64><<<2, 256, 0, stream>>>(g, NG, part);
    k_bn_adj<<<1, 64, 0, stream>>>(part, 2, NG, 64, lW, lb, 64, sc2, badj2);
    k_gemm_bn<64, 0, true, false><<<(NG + 31) / 32, 256, 0, stream>>>(
        g, lW, sc2, badj2, y, nullptr, NG, nullptr, nullptr, nullptr, nullptr, nullptr, nullptr);

    k_bn_part<64><<<2, 256, 0, stream>>>(y, NG, part);
    k_bn_adj<<<1, 64, 0, stream>>>(part, 2, NG, 64, clW, clb, 10, sc3, badj3);
    k_cls<<<NG, 64, 0, stream>>>(y, clW, sc3, badj3, out);
}

// Round 4
// 1080.377 us; speedup vs baseline: 1.2954x; 1.0883x over previous
//
#include <hip/hip_runtime.h>
#include <math.h>

#define NN 100000
#define NE 1600000
#define NG 512
#define NCLS 10
#define NEG 0.2f
#define BNEPS 1e-5f
#define BNB 1e-4f
#define MNEG -1e30f

#define NBUK 391      // buckets of 256 nodes: (NN+255)>>8
#define CHUNK2 6144   // edges per partition block
#define NB2 261       // ceil(NE/CHUNK2)
#define CAP3 5120     // per-bucket LDS capacity (avg 4092, sigma ~64)

typedef unsigned short u16;
typedef unsigned int u32;

__device__ __forceinline__ u16 f2bf(float x) {
    u32 u = __float_as_uint(x);
    u32 r = (u + 0x7fffu + ((u >> 16) & 1u)) >> 16;
    return (u16)r;
}
__device__ __forceinline__ float bf2f(u16 s) { return __uint_as_float(((u32)s) << 16); }
__device__ __forceinline__ float lrelu(float v) { return v > 0.f ? v : NEG * v; }

// ---------------- BatchNorm stats ----------------
template<int C>
__global__ __launch_bounds__(256) void k_bn_part(const float* __restrict__ x, int rows,
                                                 float* __restrict__ part) {
    const int RPI = 256 / C;
    int col = threadIdx.x % C;
    int sub = threadIdx.x / C;
    int nb = gridDim.x;
    int rpb = (rows + nb - 1) / nb;
    int r0 = blockIdx.x * rpb;
    int r1 = min(rows, r0 + rpb);
    float s = 0.f, q = 0.f;
    for (int r = r0 + sub; r < r1; r += RPI) {
        float v = x[(size_t)r * C + col];
        s += v; q += v * v;
    }
    __shared__ float ls[256], lq[256];
    ls[threadIdx.x] = s; lq[threadIdx.x] = q;
    __syncthreads();
    for (int st = RPI / 2; st > 0; st >>= 1) {
        if (sub < st) {
            ls[threadIdx.x] += ls[threadIdx.x + st * C];
            lq[threadIdx.x] += lq[threadIdx.x + st * C];
        }
        __syncthreads();
    }
    if (sub == 0) {
        part[(size_t)blockIdx.x * C + col] = ls[col];
        part[(size_t)(nb + blockIdx.x) * C + col] = lq[col];
    }
}

__global__ __launch_bounds__(64) void k_bn_adj(const float* __restrict__ part, int nb, int rows, int C,
                                               const float* __restrict__ W, const float* __restrict__ b,
                                               int Ncol, float* __restrict__ sc, float* __restrict__ badj) {
    int c = threadIdx.x;
    __shared__ float shl[64];
    if (c < C) {
        float s = 0.f, q = 0.f;
        for (int bb = 0; bb < nb; bb++) {
            s += part[(size_t)bb * C + c];
            q += part[(size_t)(nb + bb) * C + c];
        }
        float mu = s / rows;
        float var = q / rows - mu * mu;
        float sl = rsqrtf(var + BNEPS);
        sc[c] = sl;
        shl[c] = BNB - mu * sl;
    }
    __syncthreads();
    if (c < Ncol) {
        float a = b ? b[c] : 0.f;
        for (int k = 0; k < C; k++) a += shl[k] * W[(size_t)k * Ncol + c];
        badj[c] = a;
    }
}

// ---------------- fused BN+GEMM ----------------
template<int K, int EPI, bool RELU, bool OBF>
__global__ __launch_bounds__(256) void k_gemm_bn(const float* __restrict__ x, const float* __restrict__ W,
                                                 const float* __restrict__ sc, const float* __restrict__ badj,
                                                 float* __restrict__ outf, u16* __restrict__ outb, int rows,
                                                 const float* __restrict__ att, float* __restrict__ hs,
                                                 const float* __restrict__ as_, const float* __restrict__ ad_,
                                                 float* __restrict__ asrc, float* __restrict__ adst) {
    __shared__ float Ws[K * 64];
    __shared__ float Xs[32 * K];
    int r0 = blockIdx.x * 32;
    for (int i = threadIdx.x; i < K * 64; i += 256) Ws[i] = W[i];
    for (int i = threadIdx.x; i < 32 * K; i += 256) {
        int r = r0 + i / K, k = i % K;
        Xs[i] = (r < rows) ? x[(size_t)r * K + k] * sc[k] : 0.f;
    }
    __syncthreads();
    int col = threadIdx.x & 63;
    int rg = threadIdx.x >> 6;
    float b0 = badj[col];
    float acc[8];
#pragma unroll
    for (int i = 0; i < 8; i++) acc[i] = b0;
    for (int k = 0; k < K; k++) {
        float w = Ws[k * 64 + col];
#pragma unroll
        for (int i = 0; i < 8; i++) acc[i] += Xs[(rg * 8 + i) * K + k] * w;
    }
#pragma unroll
    for (int i = 0; i < 8; i++) {
        int r = r0 + rg * 8 + i;
        if (r < rows) {
            float v = RELU ? fmaxf(acc[i], 0.f) : acc[i];
            if (OBF) outb[(size_t)r * 64 + col] = f2bf(v);
            else     outf[(size_t)r * 64 + col] = v;
        }
    }
    if (EPI == 1) {
        float a = att[col];
#pragma unroll
        for (int i = 0; i < 8; i++) {
            float v = acc[i] * a;
#pragma unroll
            for (int o = 32; o; o >>= 1) v += __shfl_xor(v, o);
            int r = r0 + rg * 8 + i;
            if (col == 0 && r < rows) hs[r] = v;
        }
    }
    if (EPI == 2) {
        float a1 = as_[col], a2 = ad_[col];
#pragma unroll
        for (int i = 0; i < 8; i++) {
            float s1 = acc[i] * a1, s2 = acc[i] * a2;
#pragma unroll
            for (int o = 1; o < 16; o <<= 1) { s1 += __shfl_xor(s1, o); s2 += __shfl_xor(s2, o); }
            int r = r0 + rg * 8 + i;
            if ((col & 15) == 0 && r < rows) {
                asrc[(size_t)r * 4 + (col >> 4)] = s1;
                adst[(size_t)r * 4 + (col >> 4)] = s2;
            }
        }
    }
}

// folded attention weights
__global__ __launch_bounds__(768) void k_we(const float* __restrict__ cWe, const float* __restrict__ cae,
                                            const float* __restrict__ Wee, const float* __restrict__ att,
                                            const float* __restrict__ bee, float* __restrict__ wEbuf) {
    int t = threadIdx.x;
    int l = t >> 8;
    int h = (t >> 6) & 3;
    int k = t & 63;
    float a = 0.f;
    for (int d = 0; d < 16; d++)
        a += cWe[(size_t)l * 4096 + k * 64 + h * 16 + d] * cae[l * 64 + h * 16 + d];
    wEbuf[t] = a;
    if (t < 16) {
        float v = 0.f;
        for (int j = 0; j < 64; j++) v += Wee[t * 64 + j] * att[j];
        wEbuf[768 + t] = v;
    }
    if (t == 16) {
        float v = 0.f;
        for (int j = 0; j < 64; j++) v += bee[j] * att[j];
        wEbuf[784] = v;
    }
}

// ---------------- CSR build via LDS counting sort ----------------
__global__ __launch_bounds__(256) void k_bhist(const int* __restrict__ dst, int* __restrict__ hist) {
    __shared__ int lh[512];
    int t = threadIdx.x;
    lh[t] = 0; lh[t + 256] = 0;
    __syncthreads();
    int base = blockIdx.x * CHUNK2;
    int cnt = min(CHUNK2, NE - base);
    for (int i = t; i < cnt; i += 256) atomicAdd(&lh[dst[base + i] >> 8], 1);
    __syncthreads();
    for (int b = t; b < NBUK; b += 256) hist[blockIdx.x * NBUK + b] = lh[b];
}

__global__ __launch_bounds__(512) void k_sortscan(const int* __restrict__ hist, int* __restrict__ offs,
                                                  int* __restrict__ bucketBase, int* __restrict__ rowp) {
    __shared__ int s[512];
    int t = threadIdx.x;
    int total = 0;
    if (t < NBUK)
        for (int b = 0; b < NB2; b++) total += hist[b * NBUK + t];
    s[t] = (t < NBUK) ? total : 0;
    __syncthreads();
    for (int off = 1; off < 512; off <<= 1) {
        int v = (t >= off) ? s[t - off] : 0;
        __syncthreads();
        s[t] += v;
        __syncthreads();
    }
    if (t < NBUK) {
        int excl = s[t] - total;
        bucketBase[t] = excl;
        int run = excl;
        for (int b = 0; b < NB2; b++) {
            offs[b * NBUK + t] = run;
            run += hist[b * NBUK + t];
        }
    }
    if (t == 0) { bucketBase[NBUK] = NE; rowp[NN] = NE; }
}

// partition edges into buckets; stage in LDS so global writes are dense runs
__global__ __launch_bounds__(256) void k_part(const int* __restrict__ src, const int* __restrict__ dst,
                                              const int* __restrict__ offs, int2* __restrict__ seTmp) {
    __shared__ int lhist[512];
    __shared__ int lstart[NBUK + 1];
    __shared__ int lcur[NBUK];
    __shared__ int2 stage[CHUNK2];
    int t = threadIdx.x;
    int base = blockIdx.x * CHUNK2;
    int cnt = min(CHUNK2, NE - base);
    lhist[t] = 0; lhist[t + 256] = 0;
    __syncthreads();
    for (int i = t; i < cnt; i += 256) atomicAdd(&lhist[dst[base + i] >> 8], 1);
    __syncthreads();
    // inclusive scan of lhist[0..511]
    for (int off = 1; off < 512; off <<= 1) {
        int v0 = (t >= off) ? lhist[t - off] : 0;
        int v1 = lhist[t + 256 - off];
        __syncthreads();
        lhist[t] += v0; lhist[t + 256] += v1;
        __syncthreads();
    }
    if (t == 0) lstart[0] = 0;
    lstart[t + 1] = lhist[t];
    if (t + 257 <= NBUK) lstart[t + 257] = lhist[t + 256];
    __syncthreads();
    for (int b = t; b < NBUK; b += 256) lcur[b] = lstart[b];
    __syncthreads();
    for (int i = t; i < cnt; i += 256) {
        int e = base + i;
        int d = dst[e];
        int b = d >> 8;
        int pos = atomicAdd(&lcur[b], 1);
        int2 v; v.x = src[e]; v.y = e | ((d & 255) << 21);
        stage[pos] = v;
    }
    __syncthreads();
    int blkrow = blockIdx.x * NBUK;
    for (int q = t; q < cnt; q += 256) {
        int lo = 0, hi = NBUK;
        while (hi - lo > 1) {
            int mid = (lo + hi) >> 1;
            if (lstart[mid] <= q) lo = mid; else hi = mid;
        }
        seTmp[offs[blkrow + lo] + (q - lstart[lo])] = stage[q];
    }
}

// per-bucket fine sort in LDS; also writes rowp
__global__ __launch_bounds__(256) void k_bucket(const int2* __restrict__ seTmp,
                                                const int* __restrict__ bucketBase,
                                                int2* __restrict__ se, int* __restrict__ rowp) {
    int b = blockIdx.x;
    int t = threadIdx.x;
    int beg = bucketBase[b], end = bucketBase[b + 1];
    int cnt = end - beg;
    __shared__ int lhist[256], lscan[256], lcur[256];
    __shared__ int2 ebuf[CAP3];
    lhist[t] = 0;
    __syncthreads();
    for (int i = t; i < cnt; i += 256)
        atomicAdd(&lhist[((u32)seTmp[beg + i].y) >> 21], 1);
    __syncthreads();
    lscan[t] = lhist[t];
    __syncthreads();
    for (int off = 1; off < 256; off <<= 1) {
        int v = (t >= off) ? lscan[t - off] : 0;
        __syncthreads();
        lscan[t] += v;
        __syncthreads();
    }
    int excl = lscan[t] - lhist[t];
    lcur[t] = excl;
    int node = b * 256 + t;
    if (node < NN) rowp[node] = beg + excl;
    __syncthreads();
    if (cnt <= CAP3) {
        for (int i = t; i < cnt; i += 256) {
            int2 v = seTmp[beg + i];
            int dl = ((u32)v.y) >> 21;
            int pos = atomicAdd(&lcur[dl], 1);
            int2 o; o.x = v.x; o.y = v.y & 0x1FFFFF;
            ebuf[pos] = o;
        }
        __syncthreads();
        for (int q = t; q < cnt; q += 256) se[beg + q] = ebuf[q];
    } else {
        for (int i = t; i < cnt; i += 256) {
            int2 v = seTmp[beg + i];
            int dl = ((u32)v.y) >> 21;
            int pos = atomicAdd(&lcur[dl], 1);
            int2 o; o.x = v.x; o.y = v.y & 0x1FFFFF;
            se[beg + pos] = o;
        }
    }
}

// ---------------- edge precompute ----------------
__global__ __launch_bounds__(256) void k_edgepre(const float* __restrict__ ea, const float* __restrict__ Wee,
                                                 const float* __restrict__ bee, const float* __restrict__ wEbuf,
                                                 const int2* __restrict__ se,
                                                 float* __restrict__ heatt, float4* __restrict__ aed) {
    int p = blockIdx.x * 256 + threadIdx.x;
    if (p >= NE) return;
    int e = se[p].y;
    const float4* eav = (const float4*)(ea + (size_t)e * 16);
    float4 A0 = eav[0], A1 = eav[1], A2 = eav[2], A3 = eav[3];
    float a[16] = {A0.x, A0.y, A0.z, A0.w, A1.x, A1.y, A1.z, A1.w,
                   A2.x, A2.y, A2.z, A2.w, A3.x, A3.y, A3.z, A3.w};
    float hatt = wEbuf[784];
#pragma unroll
    for (int k = 0; k < 16; k++) hatt = fmaf(a[k], wEbuf[768 + k], hatt);
    heatt[p] = hatt;
    const float2* We2 = (const float2*)Wee;
    const float2* be2 = (const float2*)bee;
    float2 he[32];
#pragma unroll
    for (int j = 0; j < 32; j++) he[j] = be2[j];
#pragma unroll
    for (int k = 0; k < 16; k++) {
        float s = a[k];
#pragma unroll
        for (int j = 0; j < 32; j++) {
            float2 w = We2[k * 32 + j];
            he[j].x = fmaf(s, w.x, he[j].x);
            he[j].y = fmaf(s, w.y, he[j].y);
        }
    }
#pragma unroll
    for (int j = 0; j < 32; j++) {
        he[j].x = fmaxf(he[j].x, 0.f);
        he[j].y = fmaxf(he[j].y, 0.f);
    }
#pragma unroll
    for (int l = 0; l < 3; l++) {
        const float2* w0 = (const float2*)(wEbuf + (l * 4 + 0) * 64);
        const float2* w1 = (const float2*)(wEbuf + (l * 4 + 1) * 64);
        const float2* w2 = (const float2*)(wEbuf + (l * 4 + 2) * 64);
        const float2* w3 = (const float2*)(wEbuf + (l * 4 + 3) * 64);
        float s0 = 0.f, s1 = 0.f, s2 = 0.f, s3 = 0.f;
#pragma unroll
        for (int j = 0; j < 32; j++) {
            float2 r = he[j];
            float2 a0 = w0[j], a1 = w1[j], a2 = w2[j], a3 = w3[j];
            s0 += r.x * a0.x + r.y * a0.y;
            s1 += r.x * a1.x + r.y * a1.y;
            s2 += r.x * a2.x + r.y * a2.y;
            s3 += r.x * a3.x + r.y * a3.y;
        }
        float4 o; o.x = s0; o.y = s1; o.z = s2; o.w = s3;
        aed[(size_t)l * NE + p] = o;
    }
}

// ---------------- EGAT aggregation: 4 nodes/block, 1 wave/node, shuffle-only ----------------
__global__ __launch_bounds__(256) void k_egat_agg(const int* __restrict__ rowp, const int2* __restrict__ se,
                                                  const float* __restrict__ heatt, const float* __restrict__ hs,
                                                  const u16* __restrict__ hb, float* __restrict__ xout) {
    int wid = threadIdx.x >> 6, lane = threadIdx.x & 63;
    int n = blockIdx.x * 4 + wid;
    if (n >= NN) return;
    int beg = rowp[n], deg = rowp[n + 1] - beg;
    if (deg == 0) { xout[(size_t)n * 64 + lane] = 0.f; return; }
    float hsn = hs[n];
    float acc = 0.f;
    if (deg <= 64) {
        int s = 0; float lg = MNEG;
        if (lane < deg) {
            int2 pr = se[beg + lane];
            s = pr.x;
            lg = lrelu(hs[s] + hsn + heatt[beg + lane]);
        }
        float m = lg;
#pragma unroll
        for (int o = 32; o; o >>= 1) m = fmaxf(m, __shfl_xor(m, o));
        float e = (lane < deg) ? __expf(lg - m) : 0.f;
        float sm = e;
#pragma unroll
        for (int o = 32; o; o >>= 1) sm += __shfl_xor(sm, o);
        float p = e * (1.f / sm);
        int j = 0;
        for (; j + 4 <= deg; j += 4) {
            int s0 = __shfl(s, j), s1 = __shfl(s, j + 1), s2 = __shfl(s, j + 2), s3 = __shfl(s, j + 3);
            float p0 = __shfl(p, j), p1 = __shfl(p, j + 1), p2 = __shfl(p, j + 2), p3 = __shfl(p, j + 3);
            acc = fmaf(p0, bf2f(hb[(size_t)s0 * 64 + lane]), acc);
            acc = fmaf(p1, bf2f(hb[(size_t)s1 * 64 + lane]), acc);
            acc = fmaf(p2, bf2f(hb[(size_t)s2 * 64 + lane]), acc);
            acc = fmaf(p3, bf2f(hb[(size_t)s3 * 64 + lane]), acc);
        }
        for (; j < deg; j++) {
            int s0 = __shfl(s, j); float p0 = __shfl(p, j);
            acc = fmaf(p0, bf2f(hb[(size_t)s0 * 64 + lane]), acc);
        }
    } else {
        float m = MNEG, sm = 0.f;
        for (int i = lane; i < deg; i += 64) {
            int2 pr = se[beg + i];
            float v = lrelu(hs[pr.x] + hsn + heatt[beg + i]);
            float mn = fmaxf(m, v);
            sm = sm * __expf(m - mn) + __expf(v - mn);
            m = mn;
        }
#pragma unroll
        for (int o = 32; o; o >>= 1) {
            float mo = __shfl_xor(m, o), so = __shfl_xor(sm, o);
            float mn = fmaxf(m, mo);
            sm = sm * __expf(m - mn) + so * __expf(mo - mn);
            m = mn;
        }
        float inv = 1.f / sm;
        for (int base = 0; base < deg; base += 64) {
            int i = base + lane;
            int s = 0; float p = 0.f;
            if (i < deg) {
                int2 pr = se[beg + i];
                s = pr.x;
                p = __expf(lrelu(hs[s] + hsn + heatt[beg + i]) - m) * inv;
            }
            int mm = min(64, deg - base);
            for (int j = 0; j < mm; j++) {
                int s0 = __shfl(s, j); float p0 = __shfl(p, j);
                acc = fmaf(p0, bf2f(hb[(size_t)s0 * 64 + lane]), acc);
            }
        }
    }
    xout[(size_t)n * 64 + lane] = fmaxf(acc, 0.f);
}

// ---------------- conv aggregation: 4 nodes/block, 1 wave/node, per-wave LDS ----------------
__global__ __launch_bounds__(256) void k_conv_agg(const int* __restrict__ rowp, const int2* __restrict__ se,
                                                  const float4* __restrict__ aed, const float* __restrict__ asrc,
                                                  const float* __restrict__ adst, const u16* __restrict__ hb,
                                                  const float* __restrict__ bias, float* __restrict__ xout) {
    int wid = threadIdx.x >> 6, lane = threadIdx.x & 63;
    int n = blockIdx.x * 4 + wid;
    if (n >= NN) return;
    int beg = rowp[n], deg = rowp[n + 1] - beg;
    if (deg == 0) { xout[(size_t)n * 64 + lane] = fmaxf(bias[lane], 0.f); return; }
    float4 an = ((const float4*)adst)[n];
    __shared__ float pls[4][4][72];
    __shared__ int sl[4][64];
    int hq = lane >> 4;
    float acc = 0.f;
    if (deg <= 64) {
        int s = 0;
        float l0 = MNEG, l1 = MNEG, l2 = MNEG, l3 = MNEG;
        if (lane < deg) {
            s = se[beg + lane].x;
            float4 as4 = ((const float4*)asrc)[s];
            float4 ae = aed[beg + lane];
            l0 = lrelu(as4.x + an.x + ae.x);
            l1 = lrelu(as4.y + an.y + ae.y);
            l2 = lrelu(as4.z + an.z + ae.z);
            l3 = lrelu(as4.w + an.w + ae.w);
        }
        float m0 = l0, m1 = l1, m2 = l2, m3 = l3;
#pragma unroll
        for (int o = 32; o; o >>= 1) {
            m0 = fmaxf(m0, __shfl_xor(m0, o)); m1 = fmaxf(m1, __shfl_xor(m1, o));
            m2 = fmaxf(m2, __shfl_xor(m2, o)); m3 = fmaxf(m3, __shfl_xor(m3, o));
        }
        float e0 = (lane < deg) ? __expf(l0 - m0) : 0.f;
        float e1 = (lane < deg) ? __expf(l1 - m1) : 0.f;
        float e2 = (lane < deg) ? __expf(l2 - m2) : 0.f;
        float e3 = (lane < deg) ? __expf(l3 - m3) : 0.f;
        float s0 = e0, s1 = e1, s2 = e2, s3 = e3;
#pragma unroll
        for (int o = 32; o; o >>= 1) {
            s0 += __shfl_xor(s0, o); s1 += __shfl_xor(s1, o);
            s2 += __shfl_xor(s2, o); s3 += __shfl_xor(s3, o);
        }
        pls[wid][0][lane] = e0 * (1.f / s0);
        pls[wid][1][lane] = e1 * (1.f / s1);
        pls[wid][2][lane] = e2 * (1.f / s2);
        pls[wid][3][lane] = e3 * (1.f / s3);
        sl[wid][lane] = s;
        __builtin_amdgcn_wave_barrier();
        const float* prow = &pls[wid][hq][0];
        const int* srow = &sl[wid][0];
        int j = 0;
        for (; j + 4 <= deg; j += 4) {
            acc = fmaf(prow[j],     bf2f(hb[(size_t)srow[j]     * 64 + lane]), acc);
            acc = fmaf(prow[j + 1], bf2f(hb[(size_t)srow[j + 1] * 64 + lane]), acc);
            acc = fmaf(prow[j + 2], bf2f(hb[(size_t)srow[j + 2] * 64 + lane]), acc);
            acc = fmaf(prow[j + 3], bf2f(hb[(size_t)srow[j + 3] * 64 + lane]), acc);
        }
        for (; j < deg; j++) acc = fmaf(prow[j], bf2f(hb[(size_t)srow[j] * 64 + lane]), acc);
    } else {
        float m0 = MNEG, m1 = MNEG, m2 = MNEG, m3 = MNEG;
        float s0 = 0.f, s1 = 0.f, s2 = 0.f, s3 = 0.f;
        for (int i = lane; i < deg; i += 64) {
            int s = se[beg + i].x;
            float4 as4 = ((const float4*)asrc)[s];
            float4 ae = aed[beg + i];
            float l0 = lrelu(as4.x + an.x + ae.x);
            float l1 = lrelu(as4.y + an.y + ae.y);
            float l2 = lrelu(as4.z + an.z + ae.z);
            float l3 = lrelu(as4.w + an.w + ae.w);
            float n0 = fmaxf(m0, l0); s0 = s0 * __expf(m0 - n0) + __expf(l0 - n0); m0 = n0;
            float n1 = fmaxf(m1, l1); s1 = s1 * __expf(m1 - n1) + __expf(l1 - n1); m1 = n1;
            float n2 = fmaxf(m2, l2); s2 = s2 * __expf(m2 - n2) + __expf(l2 - n2); m2 = n2;
            float n3 = fmaxf(m3, l3); s3 = s3 * __expf(m3 - n3) + __expf(l3 - n3); m3 = n3;
        }
#pragma unroll
        for (int o = 32; o; o >>= 1) {
            float mo, so, mn;
            mo = __shfl_xor(m0, o); so = __shfl_xor(s0, o); mn = fmaxf(m0, mo);
            s0 = s0 * __expf(m0 - mn) + so * __expf(mo - mn); m0 = mn;
            mo = __shfl_xor(m1, o); so = __shfl_xor(s1, o); mn = fmaxf(m1, mo);
            s1 = s1 * __expf(m1 - mn) + so * __expf(mo - mn); m1 = mn;
            mo = __shfl_xor(m2, o); so = __shfl_xor(s2, o); mn = fmaxf(m2, mo);
            s2 = s2 * __expf(m2 - mn) + so * __expf(mo - mn); m2 = mn;
            mo = __shfl_xor(m3, o); so = __shfl_xor(s3, o); mn = fmaxf(m3, mo);
            s3 = s3 * __expf(m3 - mn) + so * __expf(mo - mn); m3 = mn;
        }
        float i0 = 1.f / s0, i1 = 1.f / s1, i2 = 1.f / s2, i3 = 1.f / s3;
        for (int base = 0; base < deg; base += 64) {
            int i = base + lane;
            if (i < deg) {
                int s = se[beg + i].x;
                float4 as4 = ((const float4*)asrc)[s];
                float4 ae = aed[beg + i];
                pls[wid][0][lane] = __expf(lrelu(as4.x + an.x + ae.x) - m0) * i0;
                pls[wid][1][lane] = __expf(lrelu(as4.y + an.y + ae.y) - m1) * i1;
                pls[wid][2][lane] = __expf(lrelu(as4.z + an.z + ae.z) - m2) * i2;
                pls[wid][3][lane] = __expf(lrelu(as4.w + an.w + ae.w) - m3) * i3;
                sl[wid][lane] = s;
            }
            __builtin_amdgcn_wave_barrier();
            int mm = min(64, deg - base);
            const float* prow = &pls[wid][hq][0];
            const int* srow = &sl[wid][0];
            for (int j = 0; j < mm; j++)
                acc = fmaf(prow[j], bf2f(hb[(size_t)srow[j] * 64 + lane]), acc);
            __builtin_amdgcn_wave_barrier();
        }
    }
    xout[(size_t)n * 64 + lane] = fmaxf(acc + bias[lane], 0.f);
}

// ---------------- pool + head ----------------
__device__ __forceinline__ int lowerb(const int* a, int n, int key) {
    int lo = 0, hi = n;
    while (lo < hi) {
        int mid = (lo + hi) >> 1;
        if (a[mid] < key) lo = mid + 1; else hi = mid;
    }
    return lo;
}

__global__ __launch_bounds__(256) void k_pool(const float* __restrict__ x, const int* __restrict__ batch,
                                              float* __restrict__ g) {
    int gr = blockIdx.x;
    int lane = threadIdx.x & 63;
    int sub = threadIdx.x >> 6;
    int beg = lowerb(batch, NN, gr);
    int end = lowerb(batch, NN, gr + 1);
    float acc = 0.f;
    for (int i = beg + sub; i < end; i += 4) acc += x[(size_t)i * 64 + lane];
    __shared__ float ls[4][64];
    ls[sub][lane] = acc;
    __syncthreads();
    if (sub == 0)
        g[(size_t)gr * 64 + lane] = ls[0][lane] + ls[1][lane] + ls[2][lane] + ls[3][lane];
}

__global__ __launch_bounds__(64) void k_cls(const float* __restrict__ y, const float* __restrict__ W,
                                            const float* __restrict__ sc, const float* __restrict__ badj,
                                            float* __restrict__ out) {
    int r = blockIdx.x, lane = threadIdx.x;
    __shared__ float yr[64];
    yr[lane] = y[(size_t)r * 64 + lane] * sc[lane];
    __syncthreads();
    float lg = -INFINITY;
    if (lane < NCLS) {
        float a = badj[lane];
        for (int k = 0; k < 64; k++) a += yr[k] * W[k * NCLS + lane];
        lg = a;
    }
    float mx = lg;
#pragma unroll
    for (int o = 32; o; o >>= 1) mx = fmaxf(mx, __shfl_xor(mx, o));
    float e = (lane < NCLS) ? expf(lg - mx) : 0.f;
    float s = e;
#pragma unroll
    for (int o = 32; o; o >>= 1) s += __shfl_xor(s, o);
    if (lane < NCLS) out[(size_t)r * NCLS + lane] = lg - mx - logf(s);
}

extern "C" void kernel_launch(void* const* d_in, const int* in_sizes, int n_in,
                              void* d_out, int out_size, void* d_ws, size_t ws_size,
                              hipStream_t stream) {
    const float* x0  = (const float*)d_in[0];
    const float* ea  = (const float*)d_in[1];
    const int* eidx  = (const int*)d_in[2];
    const int* batch = (const int*)d_in[3];
    const float* Wx  = (const float*)d_in[4];
    const float* bx  = (const float*)d_in[5];
    const float* Wee = (const float*)d_in[6];
    const float* bee = (const float*)d_in[7];
    const float* att = (const float*)d_in[8];
    const float* cW  = (const float*)d_in[9];
    const float* cWe = (const float*)d_in[10];
    const float* cas = (const float*)d_in[11];
    const float* cad = (const float*)d_in[12];
    const float* cae = (const float*)d_in[13];
    const float* cb  = (const float*)d_in[14];
    const float* lW  = (const float*)d_in[15];
    const float* lb  = (const float*)d_in[16];
    const float* clW = (const float*)d_in[17];
    const float* clb = (const float*)d_in[18];
    float* out = (float*)d_out;

    const int* srcA = eidx;
    const int* dstA = eidx + NE;

    char* w = (char*)d_ws;
    size_t off = 0;
    auto alloc = [&](size_t bytes) -> void* {
        void* p = w + off;
        off += (bytes + 255) & ~(size_t)255;
        return p;
    };
    u16* hbA      = (u16*)alloc((size_t)NN * 64 * 2);
    float* B      = (float*)alloc((size_t)NN * 64 * 4);
    float* hs     = (float*)alloc((size_t)NN * 4);
    float* asrc   = (float*)alloc((size_t)NN * 4 * 4);
    float* adst   = (float*)alloc((size_t)NN * 4 * 4);
    float* heatt  = (float*)alloc((size_t)NE * 4);
    float4* aed   = (float4*)alloc((size_t)3 * NE * 16);
    int2* se      = (int2*)alloc((size_t)NE * 8);
    int* rowp     = (int*)alloc((size_t)(NN + 1) * 4);
    int* hist     = (int*)alloc((size_t)NB2 * NBUK * 4);
    int* offs     = (int*)alloc((size_t)NB2 * NBUK * 4);
    int* bucketBase = (int*)alloc((size_t)(NBUK + 1) * 4);
    float* part   = (float*)alloc((size_t)2 * 200 * 64 * 4);
    float* sc     = (float*)alloc(64 * 4);
    float* badj   = (float*)alloc(64 * 4);
    float* wEbuf  = (float*)alloc(800 * 4);
    float* g      = (float*)alloc((size_t)NG * 64 * 4);
    float* y      = (float*)alloc((size_t)NG * 64 * 4);
    float* badj2  = (float*)alloc(64 * 4);
    float* badj3  = (float*)alloc(64 * 4);
    float* sc2    = (float*)alloc(64 * 4);
    float* sc3    = (float*)alloc(64 * 4);
    if (off > ws_size) return;

    int2* seTmp = (int2*)aed;  // overlay: aed unused until edgepre (after sort completes)

    const int NB = 200;

    // ---- CSR build: 3-pass LDS counting sort ----
    k_bhist<<<NB2, 256, 0, stream>>>(dstA, hist);
    k_sortscan<<<1, 512, 0, stream>>>(hist, offs, bucketBase, rowp);
    k_part<<<NB2, 256, 0, stream>>>(srcA, dstA, offs, seTmp);
    k_bucket<<<NBUK, 256, 0, stream>>>(seTmp, bucketBase, se, rowp);

    // ---- folded attention weights ----
    k_we<<<1, 768, 0, stream>>>(cWe, cae, Wee, att, bee, wEbuf);

    // ---- BN(x0) + EGAT node GEMM -> hbA (bf16) + hs epilogue ----
    k_bn_part<32><<<NB, 256, 0, stream>>>(x0, NN, part);
    k_bn_adj<<<1, 64, 0, stream>>>(part, NB, NN, 32, Wx, bx, 64, sc, badj);
    k_gemm_bn<32, 1, false, true><<<(NN + 31) / 32, 256, 0, stream>>>(
        x0, Wx, sc, badj, nullptr, hbA, NN, att, hs, nullptr, nullptr, nullptr, nullptr);

    // ---- edge precompute ----
    k_edgepre<<<(NE + 255) / 256, 256, 0, stream>>>(ea, Wee, bee, wEbuf, se, heatt, aed);

    // ---- EGAT aggregation -> B ----
    k_egat_agg<<<(NN + 3) / 4, 256, 0, stream>>>(rowp, se, heatt, hs, hbA, B);

    // ---- 3 GATConv layers ----
    for (int l = 0; l < 3; l++) {
        k_bn_part<64><<<NB, 256, 0, stream>>>(B, NN, part);
        k_bn_adj<<<1, 64, 0, stream>>>(part, NB, NN, 64, cW + (size_t)l * 4096, nullptr, 64, sc, badj);
        k_gemm_bn<64, 2, false, true><<<(NN + 31) / 32, 256, 0, stream>>>(
            B, cW + (size_t)l * 4096, sc, badj, nullptr, hbA, NN,
            nullptr, nullptr, cas + l * 64, cad + l * 64, asrc, adst);
        k_conv_agg<<<(NN + 3) / 4, 256, 0, stream>>>(rowp, se, aed + (size_t)l * NE, asrc, adst, hbA,
                                                     cb + l * 64, B);
    }

    // ---- global add pool ----
    k_pool<<<NG, 256, 0, stream>>>(B, batch, g);

    // ---- head ----
    k_bn_part<64><<<2, 256, 0, stream>>>(g, NG, part);
    k_bn_adj<<<1, 64, 0, stream>>>(part, 2, NG, 64, lW, lb, 64, sc2, badj2);
    k_gemm_bn<64, 0, true, false><<<(NG + 31) / 32, 256, 0, stream>>>(
        g, lW, sc2, badj2, y, nullptr, NG, nullptr, nullptr, nullptr, nullptr, nullptr, nullptr);

    k_bn_part<64><<<2, 256, 0, stream>>>(y, NG, part);
    k_bn_adj<<<1, 64, 0, stream>>>(part, 2, NG, 64, clW, clb, 10, sc3, badj3);
    k_cls<<<NG, 64, 0, stream>>>(y, clW, sc3, badj3, out);
}

// Round 5
// 1013.291 us; speedup vs baseline: 1.3811x; 1.0662x over previous
//
#include <hip/hip_runtime.h>
#include <math.h>

#define NN 100000
#define NE 1600000
#define NG 512
#define NCLS 10
#define NEG 0.2f
#define BNEPS 1e-5f
#define BNB 1e-4f
#define MNEG -1e30f

#define NBUK 391      // buckets of 256 nodes
#define CHUNK2 6144   // edges per partition block
#define NB2 261       // ceil(NE/CHUNK2)
#define CAP3 5120     // per-bucket LDS capacity

typedef unsigned short u16;
typedef unsigned int u32;
typedef _Float16 f16;
typedef __attribute__((ext_vector_type(8))) f16 f16x8;
typedef __attribute__((ext_vector_type(4))) float f32x4;

__device__ __forceinline__ u16 f2bf(float x) {
    u32 u = __float_as_uint(x);
    u32 r = (u + 0x7fffu + ((u >> 16) & 1u)) >> 16;
    return (u16)r;
}
__device__ __forceinline__ float bf2f(u16 s) { return __uint_as_float(((u32)s) << 16); }
__device__ __forceinline__ float lrelu(float v) { return v > 0.f ? v : NEG * v; }
__device__ __forceinline__ u16 f2h(float x) { union { u16 s; f16 h; } c; c.h = (f16)x; return c.s; }
__device__ __forceinline__ float h2f(u16 s) { union { u16 s; f16 h; } c; c.s = s; return (float)c.h; }

// ---------------- BatchNorm stats ----------------
template<int C>
__global__ __launch_bounds__(256) void k_bn_part(const float* __restrict__ x, int rows,
                                                 float* __restrict__ part) {
    const int RPI = 256 / C;
    int col = threadIdx.x % C;
    int sub = threadIdx.x / C;
    int nb = gridDim.x;
    int rpb = (rows + nb - 1) / nb;
    int r0 = blockIdx.x * rpb;
    int r1 = min(rows, r0 + rpb);
    float s = 0.f, q = 0.f;
    for (int r = r0 + sub; r < r1; r += RPI) {
        float v = x[(size_t)r * C + col];
        s += v; q += v * v;
    }
    __shared__ float ls[256], lq[256];
    ls[threadIdx.x] = s; lq[threadIdx.x] = q;
    __syncthreads();
    for (int st = RPI / 2; st > 0; st >>= 1) {
        if (sub < st) {
            ls[threadIdx.x] += ls[threadIdx.x + st * C];
            lq[threadIdx.x] += lq[threadIdx.x + st * C];
        }
        __syncthreads();
    }
    if (sub == 0) {
        part[(size_t)blockIdx.x * C + col] = ls[col];
        part[(size_t)(nb + blockIdx.x) * C + col] = lq[col];
    }
}

__global__ __launch_bounds__(64) void k_bn_adj(const float* __restrict__ part, int nb, int rows, int C,
                                               const float* __restrict__ W, const float* __restrict__ b,
                                               int Ncol, float* __restrict__ sc, float* __restrict__ badj) {
    int c = threadIdx.x;
    __shared__ float shl[64];
    if (c < C) {
        float s = 0.f, q = 0.f;
        for (int bb = 0; bb < nb; bb++) {
            s += part[(size_t)bb * C + c];
            q += part[(size_t)(nb + bb) * C + c];
        }
        float mu = s / rows;
        float var = q / rows - mu * mu;
        float sl = rsqrtf(var + BNEPS);
        sc[c] = sl;
        shl[c] = BNB - mu * sl;
    }
    __syncthreads();
    if (c < Ncol) {
        float a = b ? b[c] : 0.f;
        for (int k = 0; k < C; k++) a += shl[k] * W[(size_t)k * Ncol + c];
        badj[c] = a;
    }
}

// ---------------- fused BN+GEMM ----------------
template<int K, int EPI, bool RELU, bool OBF>
__global__ __launch_bounds__(256) void k_gemm_bn(const float* __restrict__ x, const float* __restrict__ W,
                                                 const float* __restrict__ sc, const float* __restrict__ badj,
                                                 float* __restrict__ outf, u16* __restrict__ outb, int rows,
                                                 const float* __restrict__ att, float* __restrict__ hs,
                                                 const float* __restrict__ as_, const float* __restrict__ ad_,
                                                 float* __restrict__ asrc, float* __restrict__ adst) {
    __shared__ float Ws[K * 64];
    __shared__ float Xs[32 * K];
    int r0 = blockIdx.x * 32;
    for (int i = threadIdx.x; i < K * 64; i += 256) Ws[i] = W[i];
    for (int i = threadIdx.x; i < 32 * K; i += 256) {
        int r = r0 + i / K, k = i % K;
        Xs[i] = (r < rows) ? x[(size_t)r * K + k] * sc[k] : 0.f;
    }
    __syncthreads();
    int col = threadIdx.x & 63;
    int rg = threadIdx.x >> 6;
    float b0 = badj[col];
    float acc[8];
#pragma unroll
    for (int i = 0; i < 8; i++) acc[i] = b0;
    for (int k = 0; k < K; k++) {
        float w = Ws[k * 64 + col];
#pragma unroll
        for (int i = 0; i < 8; i++) acc[i] += Xs[(rg * 8 + i) * K + k] * w;
    }
#pragma unroll
    for (int i = 0; i < 8; i++) {
        int r = r0 + rg * 8 + i;
        if (r < rows) {
            float v = RELU ? fmaxf(acc[i], 0.f) : acc[i];
            if (OBF) outb[(size_t)r * 64 + col] = f2bf(v);
            else     outf[(size_t)r * 64 + col] = v;
        }
    }
    if (EPI == 1) {
        float a = att[col];
#pragma unroll
        for (int i = 0; i < 8; i++) {
            float v = acc[i] * a;
#pragma unroll
            for (int o = 32; o; o >>= 1) v += __shfl_xor(v, o);
            int r = r0 + rg * 8 + i;
            if (col == 0 && r < rows) hs[r] = v;
        }
    }
    if (EPI == 2) {
        float a1 = as_[col], a2 = ad_[col];
#pragma unroll
        for (int i = 0; i < 8; i++) {
            float s1 = acc[i] * a1, s2 = acc[i] * a2;
#pragma unroll
            for (int o = 1; o < 16; o <<= 1) { s1 += __shfl_xor(s1, o); s2 += __shfl_xor(s2, o); }
            int r = r0 + rg * 8 + i;
            if ((col & 15) == 0 && r < rows) {
                asrc[(size_t)r * 4 + (col >> 4)] = s1;
                adst[(size_t)r * 4 + (col >> 4)] = s2;
            }
        }
    }
}

// folded attention weights + MFMA B-fragment prep
// wEbuf[0..767]=wE[12][64]; [768..783]=vatt; [784]=be.att
// Bf1[4][64][8] f16-bits: stage1 B-frags (WeT, K padded 16->32)
// Bf2[2][64][8] f16-bits: stage2 B-frags (wE as [N=16][K=64], rows>=12 zero)
__global__ __launch_bounds__(768) void k_we(const float* __restrict__ cWe, const float* __restrict__ cae,
                                            const float* __restrict__ Wee, const float* __restrict__ att,
                                            const float* __restrict__ bee, float* __restrict__ wEbuf,
                                            u16* __restrict__ Bf1, u16* __restrict__ Bf2) {
    int t = threadIdx.x;
    int l = t >> 8;
    int h = (t >> 6) & 3;
    int k = t & 63;
    float a = 0.f;
    for (int d = 0; d < 16; d++)
        a += cWe[(size_t)l * 4096 + k * 64 + h * 16 + d] * cae[l * 64 + h * 16 + d];
    wEbuf[t] = a;
    if (t < 16) {
        float v = 0.f;
        for (int j = 0; j < 64; j++) v += Wee[t * 64 + j] * att[j];
        wEbuf[768 + t] = v;
    }
    if (t == 16) {
        float v = 0.f;
        for (int j = 0; j < 64; j++) v += bee[j] * att[j];
        wEbuf[784] = v;
    }
    // Bf1: lane holds WeT[col=cb*16+(ln&15)][kk=(ln>>4)*8+j] = Wee[kk][col], kk<16 else 0
    for (int idx = t; idx < 4 * 64 * 8; idx += 768) {
        int cb = idx >> 9, ln = (idx >> 3) & 63, j = idx & 7;
        int col = cb * 16 + (ln & 15);
        int kk = (ln >> 4) * 8 + j;
        float v = (kk < 16) ? Wee[kk * 64 + col] : 0.f;
        Bf1[idx] = f2h(v);
    }
    __syncthreads();
    // Bf2: lane holds wE[n=ln&15][kk=kb*32+(ln>>4)*8+j], n<12 else 0
    for (int idx = t; idx < 2 * 64 * 8; idx += 768) {
        int kb = idx >> 9, ln = (idx >> 3) & 63, j = idx & 7;
        int n = ln & 15;
        int kk = kb * 32 + (ln >> 4) * 8 + j;
        float v = (n < 12) ? wEbuf[n * 64 + kk] : 0.f;
        Bf2[idx] = f2h(v);
    }
}

// ---------------- CSR build via LDS counting sort ----------------
__global__ __launch_bounds__(256) void k_bhist(const int* __restrict__ dst, int* __restrict__ hist) {
    __shared__ int lh[512];
    int t = threadIdx.x;
    lh[t] = 0; lh[t + 256] = 0;
    __syncthreads();
    int base = blockIdx.x * CHUNK2;
    int cnt = min(CHUNK2, NE - base);
    for (int i = t; i < cnt; i += 256) atomicAdd(&lh[dst[base + i] >> 8], 1);
    __syncthreads();
    for (int b = t; b < NBUK; b += 256) hist[blockIdx.x * NBUK + b] = lh[b];
}

__global__ __launch_bounds__(512) void k_sortscan(const int* __restrict__ hist, int* __restrict__ offs,
                                                  int* __restrict__ bucketBase, int* __restrict__ rowp) {
    __shared__ int s[512];
    int t = threadIdx.x;
    int total = 0;
    if (t < NBUK)
        for (int b = 0; b < NB2; b++) total += hist[b * NBUK + t];
    s[t] = (t < NBUK) ? total : 0;
    __syncthreads();
    for (int off = 1; off < 512; off <<= 1) {
        int v = (t >= off) ? s[t - off] : 0;
        __syncthreads();
        s[t] += v;
        __syncthreads();
    }
    if (t < NBUK) {
        int excl = s[t] - total;
        bucketBase[t] = excl;
        int run = excl;
        for (int b = 0; b < NB2; b++) {
            offs[b * NBUK + t] = run;
            run += hist[b * NBUK + t];
        }
    }
    if (t == 0) { bucketBase[NBUK] = NE; rowp[NN] = NE; }
}

__global__ __launch_bounds__(256) void k_part(const int* __restrict__ src, const int* __restrict__ dst,
                                              const int* __restrict__ offs, int2* __restrict__ seTmp) {
    __shared__ int lhist[512];
    __shared__ int lstart[NBUK + 1];
    __shared__ int lcur[NBUK];
    __shared__ int2 stage[CHUNK2];
    int t = threadIdx.x;
    int base = blockIdx.x * CHUNK2;
    int cnt = min(CHUNK2, NE - base);
    lhist[t] = 0; lhist[t + 256] = 0;
    __syncthreads();
    for (int i = t; i < cnt; i += 256) atomicAdd(&lhist[dst[base + i] >> 8], 1);
    __syncthreads();
    for (int off = 1; off < 512; off <<= 1) {
        int v0 = (t >= off) ? lhist[t - off] : 0;
        int v1 = lhist[t + 256 - off];
        __syncthreads();
        lhist[t] += v0; lhist[t + 256] += v1;
        __syncthreads();
    }
    if (t == 0) lstart[0] = 0;
    lstart[t + 1] = lhist[t];
    if (t + 257 <= NBUK) lstart[t + 257] = lhist[t + 256];
    __syncthreads();
    for (int b = t; b < NBUK; b += 256) lcur[b] = lstart[b];
    __syncthreads();
    for (int i = t; i < cnt; i += 256) {
        int e = base + i;
        int d = dst[e];
        int b = d >> 8;
        int pos = atomicAdd(&lcur[b], 1);
        int2 v; v.x = src[e]; v.y = e | ((d & 255) << 21);
        stage[pos] = v;
    }
    __syncthreads();
    int blkrow = blockIdx.x * NBUK;
    for (int q = t; q < cnt; q += 256) {
        int lo = 0, hi = NBUK;
        while (hi - lo > 1) {
            int mid = (lo + hi) >> 1;
            if (lstart[mid] <= q) lo = mid; else hi = mid;
        }
        seTmp[offs[blkrow + lo] + (q - lstart[lo])] = stage[q];
    }
}

__global__ __launch_bounds__(256) void k_bucket(const int2* __restrict__ seTmp,
                                                const int* __restrict__ bucketBase,
                                                int2* __restrict__ se, int* __restrict__ rowp) {
    int b = blockIdx.x;
    int t = threadIdx.x;
    int beg = bucketBase[b], end = bucketBase[b + 1];
    int cnt = end - beg;
    __shared__ int lhist[256], lscan[256], lcur[256];
    __shared__ int2 ebuf[CAP3];
    lhist[t] = 0;
    __syncthreads();
    for (int i = t; i < cnt; i += 256)
        atomicAdd(&lhist[((u32)seTmp[beg + i].y) >> 21], 1);
    __syncthreads();
    lscan[t] = lhist[t];
    __syncthreads();
    for (int off = 1; off < 256; off <<= 1) {
        int v = (t >= off) ? lscan[t - off] : 0;
        __syncthreads();
        lscan[t] += v;
        __syncthreads();
    }
    int excl = lscan[t] - lhist[t];
    lcur[t] = excl;
    int node = b * 256 + t;
    if (node < NN) rowp[node] = beg + excl;
    __syncthreads();
    if (cnt <= CAP3) {
        for (int i = t; i < cnt; i += 256) {
            int2 v = seTmp[beg + i];
            int dl = ((u32)v.y) >> 21;
            int pos = atomicAdd(&lcur[dl], 1);
            int2 o; o.x = v.x; o.y = v.y & 0x1FFFFF;
            ebuf[pos] = o;
        }
        __syncthreads();
        for (int q = t; q < cnt; q += 256) se[beg + q] = ebuf[q];
    } else {
        for (int i = t; i < cnt; i += 256) {
            int2 v = seTmp[beg + i];
            int dl = ((u32)v.y) >> 21;
            int pos = atomicAdd(&lcur[dl], 1);
            int2 o; o.x = v.x; o.y = v.y & 0x1FFFFF;
            se[beg + pos] = o;
        }
    }
}

// ---------------- edge precompute via MFMA (fp16 in, fp32 acc) ----------------
// wave = 16 edges. Stage1: he(16x64) = A(16x32pad) @ WeT-frags. Stage2: aed = relu(he) @ wE.
__global__ __launch_bounds__(256) void k_edgepre(const float* __restrict__ ea,
                                                 const u16* __restrict__ Bf1, const u16* __restrict__ Bf2,
                                                 const float* __restrict__ bee, const float* __restrict__ wEbuf,
                                                 const int2* __restrict__ se,
                                                 float* __restrict__ heatt, ushort4* __restrict__ aedH) {
    int wid = threadIdx.x >> 6, lane = threadIdx.x & 63;
    int gw = blockIdx.x * 4 + wid;
    int p0 = gw * 16;
    __shared__ f16 Pl[4][16][72];    // padded 144B stride -> 2-way conflicts only
    __shared__ f16 D2l[4][16][20];
    // B fragments
    f16x8 bf1[4], bf2[2];
#pragma unroll
    for (int cb = 0; cb < 4; cb++) bf1[cb] = *(const f16x8*)(Bf1 + ((size_t)cb * 64 + lane) * 8);
#pragma unroll
    for (int kb = 0; kb < 2; kb++) bf2[kb] = *(const f16x8*)(Bf2 + ((size_t)kb * 64 + lane) * 8);
    int er = lane & 15, kh = lane >> 4;
    // A fragment: lane holds edge er, k = kh*8..kh*8+7 (zero for kh>=2)
    f16x8 af = (f16x8)(f16)0.f;
    float part = 0.f;
    if (kh < 2) {
        int e = se[p0 + er].y;
        const float4* pa = (const float4*)(ea + (size_t)e * 16 + kh * 8);
        float4 v0 = pa[0], v1 = pa[1];
        af[0] = (f16)v0.x; af[1] = (f16)v0.y; af[2] = (f16)v0.z; af[3] = (f16)v0.w;
        af[4] = (f16)v1.x; af[5] = (f16)v1.y; af[6] = (f16)v1.z; af[7] = (f16)v1.w;
        const float* va = wEbuf + 768 + kh * 8;
        part = v0.x * va[0] + v0.y * va[1] + v0.z * va[2] + v0.w * va[3]
             + v1.x * va[4] + v1.y * va[5] + v1.z * va[6] + v1.w * va[7];
    }
    float po = __shfl_xor(part, 16);
    if (lane < 16) heatt[p0 + lane] = part + po + wEbuf[784];
    // stage 1
    f32x4 z = {0.f, 0.f, 0.f, 0.f};
    f32x4 d0 = __builtin_amdgcn_mfma_f32_16x16x32_f16(af, bf1[0], z, 0, 0, 0);
    f32x4 d1 = __builtin_amdgcn_mfma_f32_16x16x32_f16(af, bf1[1], z, 0, 0, 0);
    f32x4 d2_ = __builtin_amdgcn_mfma_f32_16x16x32_f16(af, bf1[2], z, 0, 0, 0);
    f32x4 d3 = __builtin_amdgcn_mfma_f32_16x16x32_f16(af, bf1[3], z, 0, 0, 0);
    // bias + relu -> P (fp16) in LDS; D layout: row=kh*4+r, col=cb*16+er
    {
        float b0 = bee[0 * 16 + er], b1 = bee[1 * 16 + er], b2 = bee[2 * 16 + er], b3 = bee[3 * 16 + er];
#pragma unroll
        for (int r = 0; r < 4; r++) {
            int row = kh * 4 + r;
            Pl[wid][row][0 * 16 + er] = (f16)fmaxf(d0[r] + b0, 0.f);
            Pl[wid][row][1 * 16 + er] = (f16)fmaxf(d1[r] + b1, 0.f);
            Pl[wid][row][2 * 16 + er] = (f16)fmaxf(d2_[r] + b2, 0.f);
            Pl[wid][row][3 * 16 + er] = (f16)fmaxf(d3[r] + b3, 0.f);
        }
    }
    __syncthreads();
    // stage 2: A-frag from P: row=er, k=kh*8..  (two K-halves)
    f16x8 pa0 = *(const f16x8*)&Pl[wid][er][kh * 8];
    f16x8 pa1 = *(const f16x8*)&Pl[wid][er][32 + kh * 8];
    f32x4 dd = __builtin_amdgcn_mfma_f32_16x16x32_f16(pa0, bf2[0], z, 0, 0, 0);
    dd = __builtin_amdgcn_mfma_f32_16x16x32_f16(pa1, bf2[1], dd, 0, 0, 0);
#pragma unroll
    for (int r = 0; r < 4; r++) D2l[wid][kh * 4 + r][er] = (f16)dd[r];
    __syncthreads();
    // write out: lane (e2, l3): aedH[l3][p0+e2] = heads 0..3 of layer l3
    int e2 = lane & 15, l3 = lane >> 4;
    if (l3 < 3) {
        ushort4 o = *(const ushort4*)&D2l[wid][e2][l3 * 4];
        aedH[(size_t)l3 * NE + p0 + e2] = o;
    }
}

// ---------------- EGAT aggregation: 4 nodes/block, 1 wave/node, shuffle-only ----------------
__global__ __launch_bounds__(256) void k_egat_agg(const int* __restrict__ rowp, const int2* __restrict__ se,
                                                  const float* __restrict__ heatt, const float* __restrict__ hs,
                                                  const u16* __restrict__ hb, float* __restrict__ xout) {
    int wid = threadIdx.x >> 6, lane = threadIdx.x & 63;
    int n = blockIdx.x * 4 + wid;
    if (n >= NN) return;
    int beg = rowp[n], deg = rowp[n + 1] - beg;
    if (deg == 0) { xout[(size_t)n * 64 + lane] = 0.f; return; }
    float hsn = hs[n];
    float acc0 = 0.f, acc1 = 0.f;
    if (deg <= 64) {
        int s = 0; float lg = MNEG;
        if (lane < deg) {
            int2 pr = se[beg + lane];
            s = pr.x;
            lg = lrelu(hs[s] + hsn + heatt[beg + lane]);
        }
        float m = lg;
#pragma unroll
        for (int o = 32; o; o >>= 1) m = fmaxf(m, __shfl_xor(m, o));
        float e = (lane < deg) ? __expf(lg - m) : 0.f;
        float sm = e;
#pragma unroll
        for (int o = 32; o; o >>= 1) sm += __shfl_xor(sm, o);
        float p = e * (1.f / sm);
        int j = 0;
        for (; j + 4 <= deg; j += 4) {
            int s0 = __shfl(s, j), s1 = __shfl(s, j + 1), s2 = __shfl(s, j + 2), s3 = __shfl(s, j + 3);
            float q0 = __shfl(p, j), q1 = __shfl(p, j + 1), q2 = __shfl(p, j + 2), q3 = __shfl(p, j + 3);
            acc0 = fmaf(q0, bf2f(hb[(size_t)s0 * 64 + lane]), acc0);
            acc1 = fmaf(q1, bf2f(hb[(size_t)s1 * 64 + lane]), acc1);
            acc0 = fmaf(q2, bf2f(hb[(size_t)s2 * 64 + lane]), acc0);
            acc1 = fmaf(q3, bf2f(hb[(size_t)s3 * 64 + lane]), acc1);
        }
        for (; j < deg; j++) {
            int s0 = __shfl(s, j); float q0 = __shfl(p, j);
            acc0 = fmaf(q0, bf2f(hb[(size_t)s0 * 64 + lane]), acc0);
        }
    } else {
        float m = MNEG, sm = 0.f;
        for (int i = lane; i < deg; i += 64) {
            int2 pr = se[beg + i];
            float v = lrelu(hs[pr.x] + hsn + heatt[beg + i]);
            float mn = fmaxf(m, v);
            sm = sm * __expf(m - mn) + __expf(v - mn);
            m = mn;
        }
#pragma unroll
        for (int o = 32; o; o >>= 1) {
            float mo = __shfl_xor(m, o), so = __shfl_xor(sm, o);
            float mn = fmaxf(m, mo);
            sm = sm * __expf(m - mn) + so * __expf(mo - mn);
            m = mn;
        }
        float inv = 1.f / sm;
        for (int base = 0; base < deg; base += 64) {
            int i = base + lane;
            int s = 0; float p = 0.f;
            if (i < deg) {
                int2 pr = se[beg + i];
                s = pr.x;
                p = __expf(lrelu(hs[s] + hsn + heatt[beg + i]) - m) * inv;
            }
            int mm = min(64, deg - base);
            for (int j = 0; j < mm; j++) {
                int s0 = __shfl(s, j); float q0 = __shfl(p, j);
                acc0 = fmaf(q0, bf2f(hb[(size_t)s0 * 64 + lane]), acc0);
            }
        }
    }
    xout[(size_t)n * 64 + lane] = fmaxf(acc0 + acc1, 0.f);
}

// ---------------- conv aggregation: 4 nodes/block, 1 wave/node ----------------
__global__ __launch_bounds__(256) void k_conv_agg(const int* __restrict__ rowp, const int2* __restrict__ se,
                                                  const ushort4* __restrict__ aedH, const float* __restrict__ asrc,
                                                  const float* __restrict__ adst, const u16* __restrict__ hb,
                                                  const float* __restrict__ bias, float* __restrict__ xout) {
    int wid = threadIdx.x >> 6, lane = threadIdx.x & 63;
    int n = blockIdx.x * 4 + wid;
    if (n >= NN) return;
    int beg = rowp[n], deg = rowp[n + 1] - beg;
    if (deg == 0) { xout[(size_t)n * 64 + lane] = fmaxf(bias[lane], 0.f); return; }
    float4 an = ((const float4*)adst)[n];
    __shared__ float pls[4][4][72];
    __shared__ int sl[4][64];
    int hq = lane >> 4;
    float acc0 = 0.f, acc1 = 0.f;
    if (deg <= 64) {
        int s = 0;
        float l0 = MNEG, l1 = MNEG, l2 = MNEG, l3 = MNEG;
        if (lane < deg) {
            s = se[beg + lane].x;
            float4 as4 = ((const float4*)asrc)[s];
            ushort4 u = aedH[beg + lane];
            l0 = lrelu(as4.x + an.x + h2f(u.x));
            l1 = lrelu(as4.y + an.y + h2f(u.y));
            l2 = lrelu(as4.z + an.z + h2f(u.z));
            l3 = lrelu(as4.w + an.w + h2f(u.w));
        }
        float m0 = l0, m1 = l1, m2 = l2, m3 = l3;
#pragma unroll
        for (int o = 32; o; o >>= 1) {
            m0 = fmaxf(m0, __shfl_xor(m0, o)); m1 = fmaxf(m1, __shfl_xor(m1, o));
            m2 = fmaxf(m2, __shfl_xor(m2, o)); m3 = fmaxf(m3, __shfl_xor(m3, o));
        }
        float e0 = (lane < deg) ? __expf(l0 - m0) : 0.f;
        float e1 = (lane < deg) ? __expf(l1 - m1) : 0.f;
        float e2 = (lane < deg) ? __expf(l2 - m2) : 0.f;
        float e3 = (lane < deg) ? __expf(l3 - m3) : 0.f;
        float s0 = e0, s1 = e1, s2 = e2, s3 = e3;
#pragma unroll
        for (int o = 32; o; o >>= 1) {
            s0 += __shfl_xor(s0, o); s1 += __shfl_xor(s1, o);
            s2 += __shfl_xor(s2, o); s3 += __shfl_xor(s3, o);
        }
        pls[wid][0][lane] = e0 * (1.f / s0);
        pls[wid][1][lane] = e1 * (1.f / s1);
        pls[wid][2][lane] = e2 * (1.f / s2);
        pls[wid][3][lane] = e3 * (1.f / s3);
        sl[wid][lane] = s;
        __builtin_amdgcn_wave_barrier();
        const float* prow = &pls[wid][hq][0];
        const int* srow = &sl[wid][0];
        int j = 0;
        for (; j + 4 <= deg; j += 4) {
            acc0 = fmaf(prow[j],     bf2f(hb[(size_t)srow[j]     * 64 + lane]), acc0);
            acc1 = fmaf(prow[j + 1], bf2f(hb[(size_t)srow[j + 1] * 64 + lane]), acc1);
            acc0 = fmaf(prow[j + 2], bf2f(hb[(size_t)srow[j + 2] * 64 + lane]), acc0);
            acc1 = fmaf(prow[j + 3], bf2f(hb[(size_t)srow[j + 3] * 64 + lane]), acc1);
        }
        for (; j < deg; j++) acc0 = fmaf(prow[j], bf2f(hb[(size_t)srow[j] * 64 + lane]), acc0);
    } else {
        float m0 = MNEG, m1 = MNEG, m2 = MNEG, m3 = MNEG;
        float s0 = 0.f, s1 = 0.f, s2 = 0.f, s3 = 0.f;
        for (int i = lane; i < deg; i += 64) {
            int s = se[beg + i].x;
            float4 as4 = ((const float4*)asrc)[s];
            ushort4 u = aedH[beg + i];
            float l0 = lrelu(as4.x + an.x + h2f(u.x));
            float l1 = lrelu(as4.y + an.y + h2f(u.y));
            float l2 = lrelu(as4.z + an.z + h2f(u.z));
            float l3 = lrelu(as4.w + an.w + h2f(u.w));
            float n0 = fmaxf(m0, l0); s0 = s0 * __expf(m0 - n0) + __expf(l0 - n0); m0 = n0;
            float n1 = fmaxf(m1, l1); s1 = s1 * __expf(m1 - n1) + __expf(l1 - n1); m1 = n1;
            float n2 = fmaxf(m2, l2); s2 = s2 * __expf(m2 - n2) + __expf(l2 - n2); m2 = n2;
            float n3 = fmaxf(m3, l3); s3 = s3 * __expf(m3 - n3) + __expf(l3 - n3); m3 = n3;
        }
#pragma unroll
        for (int o = 32; o; o >>= 1) {
            float mo, so, mn;
            mo = __shfl_xor(m0, o); so = __shfl_xor(s0, o); mn = fmaxf(m0, mo);
            s0 = s0 * __expf(m0 - mn) + so * __expf(mo - mn); m0 = mn;
            mo = __shfl_xor(m1, o); so = __shfl_xor(s1, o); mn = fmaxf(m1, mo);
            s1 = s1 * __expf(m1 - mn) + so * __expf(mo - mn); m1 = mn;
            mo = __shfl_xor(m2, o); so = __shfl_xor(s2, o); mn = fmaxf(m2, mo);
            s2 = s2 * __expf(m2 - mn) + so * __expf(mo - mn); m2 = mn;
            mo = __shfl_xor(m3, o); so = __shfl_xor(s3, o); mn = fmaxf(m3, mo);
            s3 = s3 * __expf(m3 - mn) + so * __expf(mo - mn); m3 = mn;
        }
        float i0 = 1.f / s0, i1 = 1.f / s1, i2 = 1.f / s2, i3 = 1.f / s3;
        for (int base = 0; base < deg; base += 64) {
            int i = base + lane;
            if (i < deg) {
                int s = se[beg + i].x;
                float4 as4 = ((const float4*)asrc)[s];
                ushort4 u = aedH[beg + i];
                pls[wid][0][lane] = __expf(lrelu(as4.x + an.x + h2f(u.x)) - m0) * i0;
                pls[wid][1][lane] = __expf(lrelu(as4.y + an.y + h2f(u.y)) - m1) * i1;
                pls[wid][2][lane] = __expf(lrelu(as4.z + an.z + h2f(u.z)) - m2) * i2;
                pls[wid][3][lane] = __expf(lrelu(as4.w + an.w + h2f(u.w)) - m3) * i3;
                sl[wid][lane] = s;
            }
            __builtin_amdgcn_wave_barrier();
            int mm = min(64, deg - base);
            const float* prow = &pls[wid][hq][0];
            const int* srow = &sl[wid][0];
            for (int j = 0; j < mm; j++)
                acc0 = fmaf(prow[j], bf2f(hb[(size_t)srow[j] * 64 + lane]), acc0);
            __builtin_amdgcn_wave_barrier();
        }
    }
    xout[(size_t)n * 64 + lane] = fmaxf(acc0 + acc1 + bias[lane], 0.f);
}

// ---------------- pool + head ----------------
__device__ __forceinline__ int lowerb(const int* a, int n, int key) {
    int lo = 0, hi = n;
    while (lo < hi) {
        int mid = (lo + hi) >> 1;
        if (a[mid] < key) lo = mid + 1; else hi = mid;
    }
    return lo;
}

__global__ __launch_bounds__(256) void k_pool(const float* __restrict__ x, const int* __restrict__ batch,
                                              float* __restrict__ g) {
    int gr = blockIdx.x;
    int lane = threadIdx.x & 63;
    int sub = threadIdx.x >> 6;
    int beg = lowerb(batch, NN, gr);
    int end = lowerb(batch, NN, gr + 1);
    float acc = 0.f;
    for (int i = beg + sub; i < end; i += 4) acc += x[(size_t)i * 64 + lane];
    __shared__ float ls[4][64];
    ls[sub][lane] = acc;
    __syncthreads();
    if (sub == 0)
        g[(size_t)gr * 64 + lane] = ls[0][lane] + ls[1][lane] + ls[2][lane] + ls[3][lane];
}

__global__ __launch_bounds__(64) void k_cls(const float* __restrict__ y, const float* __restrict__ W,
                                            const float* __restrict__ sc, const float* __restrict__ badj,
                                            float* __restrict__ out) {
    int r = blockIdx.x, lane = threadIdx.x;
    __shared__ float yr[64];
    yr[lane] = y[(size_t)r * 64 + lane] * sc[lane];
    __syncthreads();
    float lg = -INFINITY;
    if (lane < NCLS) {
        float a = badj[lane];
        for (int k = 0; k < 64; k++) a += yr[k] * W[k * NCLS + lane];
        lg = a;
    }
    float mx = lg;
#pragma unroll
    for (int o = 32; o; o >>= 1) mx = fmaxf(mx, __shfl_xor(mx, o));
    float e = (lane < NCLS) ? expf(lg - mx) : 0.f;
    float s = e;
#pragma unroll
    for (int o = 32; o; o >>= 1) s += __shfl_xor(s, o);
    if (lane < NCLS) out[(size_t)r * NCLS + lane] = lg - mx - logf(s);
}

extern "C" void kernel_launch(void* const* d_in, const int* in_sizes, int n_in,
                              void* d_out, int out_size, void* d_ws, size_t ws_size,
                              hipStream_t stream) {
    const float* x0  = (const float*)d_in[0];
    const float* ea  = (const float*)d_in[1];
    const int* eidx  = (const int*)d_in[2];
    const int* batch = (const int*)d_in[3];
    const float* Wx  = (const float*)d_in[4];
    const float* bx  = (const float*)d_in[5];
    const float* Wee = (const float*)d_in[6];
    const float* bee = (const float*)d_in[7];
    const float* att = (const float*)d_in[8];
    const float* cW  = (const float*)d_in[9];
    const float* cWe = (const float*)d_in[10];
    const float* cas = (const float*)d_in[11];
    const float* cad = (const float*)d_in[12];
    const float* cae = (const float*)d_in[13];
    const float* cb  = (const float*)d_in[14];
    const float* lW  = (const float*)d_in[15];
    const float* lb  = (const float*)d_in[16];
    const float* clW = (const float*)d_in[17];
    const float* clb = (const float*)d_in[18];
    float* out = (float*)d_out;

    const int* srcA = eidx;
    const int* dstA = eidx + NE;

    char* w = (char*)d_ws;
    size_t off = 0;
    auto alloc = [&](size_t bytes) -> void* {
        void* p = w + off;
        off += (bytes + 255) & ~(size_t)255;
        return p;
    };
    u16* hbA      = (u16*)alloc((size_t)NN * 64 * 2);
    float* B      = (float*)alloc((size_t)NN * 64 * 4);
    float* hs     = (float*)alloc((size_t)NN * 4);
    float* asrc   = (float*)alloc((size_t)NN * 4 * 4);
    float* adst   = (float*)alloc((size_t)NN * 4 * 4);
    float* heatt  = (float*)alloc((size_t)NE * 4);
    ushort4* aedH = (ushort4*)alloc((size_t)3 * NE * 8);
    int2* se      = (int2*)alloc((size_t)NE * 8);
    int* rowp     = (int*)alloc((size_t)(NN + 1) * 4);
    int* hist     = (int*)alloc((size_t)NB2 * NBUK * 4);
    int* offs     = (int*)alloc((size_t)NB2 * NBUK * 4);
    int* bucketBase = (int*)alloc((size_t)(NBUK + 1) * 4);
    float* part   = (float*)alloc((size_t)2 * 200 * 64 * 4);
    float* sc     = (float*)alloc(64 * 4);
    float* badj   = (float*)alloc(64 * 4);
    float* wEbuf  = (float*)alloc(800 * 4);
    u16* Bf1      = (u16*)alloc(4 * 64 * 8 * 2);
    u16* Bf2      = (u16*)alloc(2 * 64 * 8 * 2);
    float* g      = (float*)alloc((size_t)NG * 64 * 4);
    float* y      = (float*)alloc((size_t)NG * 64 * 4);
    float* badj2  = (float*)alloc(64 * 4);
    float* badj3  = (float*)alloc(64 * 4);
    float* sc2    = (float*)alloc(64 * 4);
    float* sc3    = (float*)alloc(64 * 4);
    if (off > ws_size) return;

    int2* seTmp = (int2*)aedH;  // overlay: aedH unused until edgepre

    const int NB = 200;

    // ---- CSR build: 3-pass LDS counting sort ----
    k_bhist<<<NB2, 256, 0, stream>>>(dstA, hist);
    k_sortscan<<<1, 512, 0, stream>>>(hist, offs, bucketBase, rowp);
    k_part<<<NB2, 256, 0, stream>>>(srcA, dstA, offs, seTmp);
    k_bucket<<<NBUK, 256, 0, stream>>>(seTmp, bucketBase, se, rowp);

    // ---- folded attention weights + MFMA frags ----
    k_we<<<1, 768, 0, stream>>>(cWe, cae, Wee, att, bee, wEbuf, Bf1, Bf2);

    // ---- BN(x0) + EGAT node GEMM -> hbA (bf16) + hs epilogue ----
    k_bn_part<32><<<NB, 256, 0, stream>>>(x0, NN, part);
    k_bn_adj<<<1, 64, 0, stream>>>(part, NB, NN, 32, Wx, bx, 64, sc, badj);
    k_gemm_bn<32, 1, false, true><<<(NN + 31) / 32, 256, 0, stream>>>(
        x0, Wx, sc, badj, nullptr, hbA, NN, att, hs, nullptr, nullptr, nullptr, nullptr);

    // ---- edge precompute (MFMA) ----
    k_edgepre<<<NE / 64, 256, 0, stream>>>(ea, Bf1, Bf2, bee, wEbuf, se, heatt, aedH);

    // ---- EGAT aggregation -> B ----
    k_egat_agg<<<(NN + 3) / 4, 256, 0, stream>>>(rowp, se, heatt, hs, hbA, B);

    // ---- 3 GATConv layers ----
    for (int l = 0; l < 3; l++) {
        k_bn_part<64><<<NB, 256, 0, stream>>>(B, NN, part);
        k_bn_adj<<<1, 64, 0, stream>>>(part, NB, NN, 64, cW + (size_t)l * 4096, nullptr, 64, sc, badj);
        k_gemm_bn<64, 2, false, true><<<(NN + 31) / 32, 256, 0, stream>>>(
            B, cW + (size_t)l * 4096, sc, badj, nullptr, hbA, NN,
            nullptr, nullptr, cas + l * 64, cad + l * 64, asrc, adst);
        k_conv_agg<<<(NN + 3) / 4, 256, 0, stream>>>(rowp, se, aedH + (size_t)l * NE, asrc, adst, hbA,
                                                     cb + l * 64, B);
    }

    // ---- global add pool ----
    k_pool<<<NG, 256, 0, stream>>>(B, batch, g);

    // ---- head ----
    k_bn_part<64><<<2, 256, 0, stream>>>(g, NG, part);
    k_bn_adj<<<1, 64, 0, stream>>>(part, 2, NG, 64, lW, lb, 64, sc2, badj2);
    k_gemm_bn<64, 0, true, false><<<(NG + 31) / 32, 256, 0, stream>>>(
        g, lW, sc2, badj2, y, nullptr, NG, nullptr, nullptr, nullptr, nullptr, nullptr, nullptr);

    k_bn_part<64><<<2, 256, 0, stream>>>(y, NG, part);
    k_bn_adj<<<1, 64, 0, stream>>>(part, 2, NG, 64, clW, clb, 10, sc3, badj3);
    k_cls<<<NG, 64, 0, stream>>>(y, clW, sc3, badj3, out);
}